// Round 1
// baseline (1989.760 us; speedup 1.0000x reference)
//
#include <hip/hip_runtime.h>

#define N_NODES 100000
#define NE      1600000
#define DIM     128
#define ODIM    64
#define NORDER  4   // ORDER

// ---------------------------------------------------------------------------
// CSR build kernels
// ---------------------------------------------------------------------------
__global__ __launch_bounds__(256) void zero_cnt(int* __restrict__ cnt) {
    int i = blockIdx.x * 256 + threadIdx.x;
    if (i < N_NODES) cnt[i] = 0;
}

__global__ __launch_bounds__(256) void count_edges(const int* __restrict__ colp,
                                                   int* __restrict__ cnt) {
    int e = blockIdx.x * 256 + threadIdx.x;
    if (e < NE) atomicAdd(&cnt[colp[e]], 1);
}

// per-block exclusive scan over 1024 elements (256 thr x 4 items)
__global__ __launch_bounds__(256) void scan_block(const int* __restrict__ cnt,
                                                  int* __restrict__ excl,
                                                  int* __restrict__ bsum) {
    __shared__ int lds[256];
    int t = threadIdx.x, b = blockIdx.x;
    int base = b * 1024 + t * 4;
    int v0 = (base + 0 < N_NODES) ? cnt[base + 0] : 0;
    int v1 = (base + 1 < N_NODES) ? cnt[base + 1] : 0;
    int v2 = (base + 2 < N_NODES) ? cnt[base + 2] : 0;
    int v3 = (base + 3 < N_NODES) ? cnt[base + 3] : 0;
    int tot = v0 + v1 + v2 + v3;
    lds[t] = tot;
    __syncthreads();
    for (int off = 1; off < 256; off <<= 1) {
        int x = (t >= off) ? lds[t - off] : 0;
        __syncthreads();
        lds[t] += x;
        __syncthreads();
    }
    int run = lds[t] - tot;   // exclusive prefix of this thread
    if (t == 255) bsum[b] = lds[255];
    if (base + 0 < N_NODES) excl[base + 0] = run; run += v0;
    if (base + 1 < N_NODES) excl[base + 1] = run; run += v1;
    if (base + 2 < N_NODES) excl[base + 2] = run; run += v2;
    if (base + 3 < N_NODES) excl[base + 3] = run;
}

__global__ void scan_mid(int* __restrict__ bsum, int nb) {
    if (threadIdx.x == 0 && blockIdx.x == 0) {
        int run = 0;
        for (int i = 0; i < nb; ++i) { int x = bsum[i]; bsum[i] = run; run += x; }
    }
}

// ptr[i] += bsum[i/1024]; dinv[i] = rsqrt(cnt[i]+1); cnt[i]=0; ptr[N]=NE
__global__ __launch_bounds__(256) void scan_add(int* __restrict__ ptrv,
                                                const int* __restrict__ bsum,
                                                int* __restrict__ cnt,
                                                float* __restrict__ dinv) {
    int i = blockIdx.x * 256 + threadIdx.x;
    if (i < N_NODES) {
        int c = cnt[i];
        dinv[i] = rsqrtf((float)(c + 1));
        ptrv[i] += bsum[i >> 10];
        cnt[i] = 0;
    }
    if (i == 0) ptrv[N_NODES] = NE;
}

__global__ __launch_bounds__(256) void fill_csr(const int* __restrict__ rowp,
                                                const int* __restrict__ colp,
                                                const int* __restrict__ ptrv,
                                                int* __restrict__ cnt,
                                                int* __restrict__ src,
                                                float* __restrict__ wgt,
                                                const float* __restrict__ dinv) {
    int e = blockIdx.x * 256 + threadIdx.x;
    if (e < NE) {
        int c = colp[e];
        int r = rowp[e];
        int pos = ptrv[c] + atomicAdd(&cnt[c], 1);
        src[pos] = r;
        wgt[pos] = dinv[r] * dinv[c];
    }
}

// ---------------------------------------------------------------------------
// Propagation: Tout[v] = dinv[v]^2 * Tin[v] + sum_e w_e * Tin[src_e]
// one wave (64 lanes) per node, float2 per lane (128 dims)
// ---------------------------------------------------------------------------
__global__ __launch_bounds__(256) void propagate(const float* __restrict__ Tin,
                                                 float* __restrict__ Tout,
                                                 const int* __restrict__ ptrv,
                                                 const int* __restrict__ src,
                                                 const float* __restrict__ wgt,
                                                 const float* __restrict__ dinv) {
    int gid  = blockIdx.x * 256 + threadIdx.x;
    int v    = gid >> 6;
    int lane = threadIdx.x & 63;
    if (v >= N_NODES) return;
    const float2* T2 = (const float2*)Tin;
    float dv = dinv[v];
    float2 self = T2[v * 64 + lane];
    float ax = dv * dv * self.x;
    float ay = dv * dv * self.y;
    int beg = ptrv[v], end = ptrv[v + 1];
    int k = beg;
    int n4 = beg + ((end - beg) & ~3);
    for (; k < n4; k += 4) {
        int u0 = src[k], u1 = src[k + 1], u2 = src[k + 2], u3 = src[k + 3];
        float w0 = wgt[k], w1 = wgt[k + 1], w2 = wgt[k + 2], w3 = wgt[k + 3];
        float2 t0 = T2[u0 * 64 + lane];
        float2 t1 = T2[u1 * 64 + lane];
        float2 t2 = T2[u2 * 64 + lane];
        float2 t3 = T2[u3 * 64 + lane];
        ax += w0 * t0.x; ay += w0 * t0.y;
        ax += w1 * t1.x; ay += w1 * t1.y;
        ax += w2 * t2.x; ay += w2 * t2.y;
        ax += w3 * t3.x; ay += w3 * t3.y;
    }
    for (; k < end; ++k) {
        int u = src[k]; float w = wgt[k];
        float2 t = T2[u * 64 + lane];
        ax += w * t.x; ay += w * t.y;
    }
    ((float2*)Tout)[v * 64 + lane] = make_float2(ax, ay);
}

// ---------------------------------------------------------------------------
// C[r][c] (+)= A[r][:] @ W[:][c]   A: N x 128, W: 128 x 128
// block: 256 thr = 4 waves, 32 rows/block, 3125 blocks
// ---------------------------------------------------------------------------
__global__ __launch_bounds__(256) void gemm_acc128(const float* __restrict__ A,
                                                   const float* __restrict__ W,
                                                   float* __restrict__ C,
                                                   int init) {
    __shared__ float Wl[DIM * DIM];   // 64 KB
    __shared__ float Al[32 * DIM];    // 16 KB
    int t = threadIdx.x;
    int rowBase = blockIdx.x * 32;
    for (int i = 0; i < 16; ++i) {
        int idx = (i * 256 + t) * 4;
        *(float4*)&Wl[idx] = *(const float4*)&W[idx];
    }
    const float* Ab = A + rowBase * DIM;
    for (int i = 0; i < 4; ++i) {
        int idx = (i * 256 + t) * 4;
        *(float4*)&Al[idx] = *(const float4*)&Ab[idx];
    }
    __syncthreads();
    int lane = t & 63, w = t >> 6;
    int c4 = (lane & 31) * 4;
    int r0 = w * 8 + (lane >> 5) * 4;
    float4 acc0, acc1, acc2, acc3;
    if (init) {
        acc0 = acc1 = acc2 = acc3 = make_float4(0.f, 0.f, 0.f, 0.f);
    } else {
        acc0 = *(const float4*)&C[(rowBase + r0 + 0) * DIM + c4];
        acc1 = *(const float4*)&C[(rowBase + r0 + 1) * DIM + c4];
        acc2 = *(const float4*)&C[(rowBase + r0 + 2) * DIM + c4];
        acc3 = *(const float4*)&C[(rowBase + r0 + 3) * DIM + c4];
    }
    for (int k0 = 0; k0 < DIM; k0 += 4) {
        float4 a0 = *(const float4*)&Al[(r0 + 0) * DIM + k0];
        float4 a1 = *(const float4*)&Al[(r0 + 1) * DIM + k0];
        float4 a2 = *(const float4*)&Al[(r0 + 2) * DIM + k0];
        float4 a3 = *(const float4*)&Al[(r0 + 3) * DIM + k0];
#define GSTEP(comp, kk)                                                      \
        {                                                                    \
            float4 wv = *(const float4*)&Wl[(k0 + kk) * DIM + c4];           \
            acc0.x += a0.comp * wv.x; acc0.y += a0.comp * wv.y;              \
            acc0.z += a0.comp * wv.z; acc0.w += a0.comp * wv.w;              \
            acc1.x += a1.comp * wv.x; acc1.y += a1.comp * wv.y;              \
            acc1.z += a1.comp * wv.z; acc1.w += a1.comp * wv.w;              \
            acc2.x += a2.comp * wv.x; acc2.y += a2.comp * wv.y;              \
            acc2.z += a2.comp * wv.z; acc2.w += a2.comp * wv.w;              \
            acc3.x += a3.comp * wv.x; acc3.y += a3.comp * wv.y;              \
            acc3.z += a3.comp * wv.z; acc3.w += a3.comp * wv.w;              \
        }
        GSTEP(x, 0) GSTEP(y, 1) GSTEP(z, 2) GSTEP(w, 3)
#undef GSTEP
    }
    *(float4*)&C[(rowBase + r0 + 0) * DIM + c4] = acc0;
    *(float4*)&C[(rowBase + r0 + 1) * DIM + c4] = acc1;
    *(float4*)&C[(rowBase + r0 + 2) * DIM + c4] = acc2;
    *(float4*)&C[(rowBase + r0 + 3) * DIM + c4] = acc3;
}

// ---------------------------------------------------------------------------
// out = (w0*relu(accO + sum(bO)) + w1*relu(accA + sum(bA))) @ clfW + clfB
// block: 256 thr, 32 rows/block
// ---------------------------------------------------------------------------
__global__ __launch_bounds__(256) void fuse_clf(const float* __restrict__ accO,
                                                const float* __restrict__ accA,
                                                const float* __restrict__ bO,
                                                const float* __restrict__ bA,
                                                const float* __restrict__ fw,
                                                const float* __restrict__ clfW,
                                                const float* __restrict__ clfB,
                                                float* __restrict__ out) {
    __shared__ float Wl[DIM * ODIM];  // 32 KB
    __shared__ float Hl[32 * DIM];    // 16 KB
    __shared__ float bs[2][DIM];
    int t = threadIdx.x;
    float f0 = fw[0], f1 = fw[1];
    float m = fmaxf(f0, f1);
    float e0 = expf(f0 - m), e1 = expf(f1 - m);
    float sw0 = e0 / (e0 + e1), sw1 = e1 / (e0 + e1);
    if (t < 128) {
        float s = 0.f;
        for (int i = 0; i <= NORDER; ++i) s += bO[i * DIM + t];
        bs[0][t] = s;
    } else {
        int j = t - 128;
        float s = 0.f;
        for (int i = 0; i <= NORDER; ++i) s += bA[i * DIM + j];
        bs[1][j] = s;
    }
    for (int i = 0; i < 8; ++i) {
        int idx = (i * 256 + t) * 4;
        *(float4*)&Wl[idx] = *(const float4*)&clfW[idx];
    }
    __syncthreads();
    int rowBase = blockIdx.x * 32;
    for (int i = 0; i < 4; ++i) {
        int idx = (i * 256 + t) * 4;
        int kcol = idx & 127;
        float4 a = *(const float4*)&accO[rowBase * DIM + idx];
        float4 b = *(const float4*)&accA[rowBase * DIM + idx];
        float4 h;
        h.x = sw0 * fmaxf(a.x + bs[0][kcol + 0], 0.f) + sw1 * fmaxf(b.x + bs[1][kcol + 0], 0.f);
        h.y = sw0 * fmaxf(a.y + bs[0][kcol + 1], 0.f) + sw1 * fmaxf(b.y + bs[1][kcol + 1], 0.f);
        h.z = sw0 * fmaxf(a.z + bs[0][kcol + 2], 0.f) + sw1 * fmaxf(b.z + bs[1][kcol + 2], 0.f);
        h.w = sw0 * fmaxf(a.w + bs[0][kcol + 3], 0.f) + sw1 * fmaxf(b.w + bs[1][kcol + 3], 0.f);
        *(float4*)&Hl[idx] = h;
    }
    __syncthreads();
    int lane = t & 63, w = t >> 6;
    int c2 = (lane & 31) * 2;
    int r0 = w * 8 + (lane >> 5) * 4;
    float acc[4][2];
    for (int j = 0; j < 4; ++j) { acc[j][0] = 0.f; acc[j][1] = 0.f; }
    for (int k0 = 0; k0 < DIM; k0 += 4) {
        float4 a0 = *(const float4*)&Hl[(r0 + 0) * DIM + k0];
        float4 a1 = *(const float4*)&Hl[(r0 + 1) * DIM + k0];
        float4 a2 = *(const float4*)&Hl[(r0 + 2) * DIM + k0];
        float4 a3 = *(const float4*)&Hl[(r0 + 3) * DIM + k0];
#define FSTEP(comp, kk)                                                      \
        {                                                                    \
            float2 wv = *(const float2*)&Wl[(k0 + kk) * ODIM + c2];          \
            acc[0][0] += a0.comp * wv.x; acc[0][1] += a0.comp * wv.y;        \
            acc[1][0] += a1.comp * wv.x; acc[1][1] += a1.comp * wv.y;        \
            acc[2][0] += a2.comp * wv.x; acc[2][1] += a2.comp * wv.y;        \
            acc[3][0] += a3.comp * wv.x; acc[3][1] += a3.comp * wv.y;        \
        }
        FSTEP(x, 0) FSTEP(y, 1) FSTEP(z, 2) FSTEP(w, 3)
#undef FSTEP
    }
    float2 cb2 = *(const float2*)&clfB[c2];
    for (int j = 0; j < 4; ++j) {
        float2 o = make_float2(acc[j][0] + cb2.x, acc[j][1] + cb2.y);
        *(float2*)&out[(rowBase + r0 + j) * ODIM + c2] = o;
    }
}

// ---------------------------------------------------------------------------
extern "C" void kernel_launch(void* const* d_in, const int* in_sizes, int n_in,
                              void* d_out, int out_size, void* d_ws, size_t ws_size,
                              hipStream_t stream) {
    const float* x   = (const float*)d_in[0];
    const int*   ei  = (const int*)d_in[1];
    const int*   gi  = (const int*)d_in[2];
    const float* w_o = (const float*)d_in[3];
    const float* b_o = (const float*)d_in[4];
    const float* w_a = (const float*)d_in[5];
    const float* b_a = (const float*)d_in[6];
    const float* fw  = (const float*)d_in[7];
    const float* cw  = (const float*)d_in[8];
    const float* cb  = (const float*)d_in[9];
    float* out = (float*)d_out;

    char* p = (char*)d_ws;
    auto alloc = [&](size_t bytes) {
        void* r = (void*)p;
        p += (bytes + 255) & ~(size_t)255;
        return r;
    };
    float* acc_o   = (float*)alloc((size_t)N_NODES * DIM * 4);
    float* acc_a   = (float*)alloc((size_t)N_NODES * DIM * 4);
    float* Ta      = (float*)alloc((size_t)N_NODES * DIM * 4);
    float* Tb      = (float*)alloc((size_t)N_NODES * DIM * 4);
    float* dinv    = (float*)alloc((size_t)N_NODES * 4);
    float* csr_w   = (float*)alloc((size_t)NE * 4);
    int*   csr_src = (int*)alloc((size_t)NE * 4);
    int*   csr_ptr = (int*)alloc((size_t)(N_NODES + 1) * 4);
    int*   cnt     = (int*)alloc((size_t)N_NODES * 4);
    int*   bsum    = (int*)alloc(128 * 4);

    const int gN  = (N_NODES + 255) / 256;   // 391
    const int gE  = (NE + 255) / 256;        // 6250
    const int gS  = (N_NODES + 1023) / 1024; // 98
    const int gP  = (N_NODES * 64 + 255) / 256; // 25000
    const int gG  = N_NODES / 32;            // 3125

    for (int g = 0; g < 2; ++g) {
        const int*   edges = g ? gi : ei;
        const float* W     = g ? w_a : w_o;
        float*       acc   = g ? acc_a : acc_o;
        const int* rowp = edges;
        const int* colp = edges + NE;

        zero_cnt<<<gN, 256, 0, stream>>>(cnt);
        count_edges<<<gE, 256, 0, stream>>>(colp, cnt);
        scan_block<<<gS, 256, 0, stream>>>(cnt, csr_ptr, bsum);
        scan_mid<<<1, 64, 0, stream>>>(bsum, gS);
        scan_add<<<gN, 256, 0, stream>>>(csr_ptr, bsum, cnt, dinv);
        fill_csr<<<gE, 256, 0, stream>>>(rowp, colp, csr_ptr, cnt, csr_src, csr_w, dinv);

        gemm_acc128<<<gG, 256, 0, stream>>>(x, W, acc, 1);
        const float* Tcur = x;
        float* Tnext = Ta;
        for (int i = 1; i <= NORDER; ++i) {
            propagate<<<gP, 256, 0, stream>>>(Tcur, Tnext, csr_ptr, csr_src, csr_w, dinv);
            gemm_acc128<<<gG, 256, 0, stream>>>(Tnext, W + (size_t)i * DIM * DIM, acc, 0);
            Tcur = Tnext;
            Tnext = (Tnext == Ta) ? Tb : Ta;
        }
    }
    fuse_clf<<<gG, 256, 0, stream>>>(acc_o, acc_a, b_o, b_a, fw, cw, cb, out);
}

// Round 2
// 1338.811 us; speedup vs baseline: 1.4862x; 1.4862x over previous
//
#include <hip/hip_runtime.h>

#define N_NODES 100000
#define NPAD    100032      // padded to multiple of 64 for GEMM tiles
#define NE      1600000
#define DIM     128
#define ODIM    64
#define NORDER  4

typedef _Float16 h8 __attribute__((ext_vector_type(8)));
typedef float f4 __attribute__((ext_vector_type(4)));

__device__ __forceinline__ float2 up2(unsigned p) {
    union { unsigned u; _Float16 h[2]; } c; c.u = p;
    return make_float2((float)c.h[0], (float)c.h[1]);
}
__device__ __forceinline__ unsigned pk2(float x, float y) {
    union { unsigned u; _Float16 h[2]; } c;
    c.h[0] = (_Float16)x; c.h[1] = (_Float16)y;
    return c.u;
}
__device__ __forceinline__ unsigned short f2hbits(float x) {
    union { _Float16 h; unsigned short s; } c;
    c.h = (_Float16)x;
    return c.s;
}

// ---------------------------------------------------------------------------
// CSR build
// ---------------------------------------------------------------------------
__global__ __launch_bounds__(256) void zero_cnt(int* __restrict__ cnt) {
    int i = blockIdx.x * 256 + threadIdx.x;
    if (i < N_NODES) cnt[i] = 0;
}

__global__ __launch_bounds__(256) void count_edges(const int* __restrict__ colp,
                                                   int* __restrict__ cnt) {
    int e = blockIdx.x * 256 + threadIdx.x;
    if (e < NE) atomicAdd(&cnt[colp[e]], 1);
}

__global__ __launch_bounds__(256) void scan_block(const int* __restrict__ cnt,
                                                  int* __restrict__ excl,
                                                  int* __restrict__ bsum) {
    __shared__ int lds[256];
    int t = threadIdx.x, b = blockIdx.x;
    int base = b * 1024 + t * 4;
    int v0 = (base + 0 < N_NODES) ? cnt[base + 0] : 0;
    int v1 = (base + 1 < N_NODES) ? cnt[base + 1] : 0;
    int v2 = (base + 2 < N_NODES) ? cnt[base + 2] : 0;
    int v3 = (base + 3 < N_NODES) ? cnt[base + 3] : 0;
    int tot = v0 + v1 + v2 + v3;
    lds[t] = tot;
    __syncthreads();
    for (int off = 1; off < 256; off <<= 1) {
        int x = (t >= off) ? lds[t - off] : 0;
        __syncthreads();
        lds[t] += x;
        __syncthreads();
    }
    int run = lds[t] - tot;
    if (t == 255) bsum[b] = lds[255];
    if (base + 0 < N_NODES) excl[base + 0] = run; run += v0;
    if (base + 1 < N_NODES) excl[base + 1] = run; run += v1;
    if (base + 2 < N_NODES) excl[base + 2] = run; run += v2;
    if (base + 3 < N_NODES) excl[base + 3] = run;
}

__global__ void scan_mid(int* __restrict__ bsum, int nb) {
    if (threadIdx.x == 0 && blockIdx.x == 0) {
        int run = 0;
        for (int i = 0; i < nb; ++i) { int x = bsum[i]; bsum[i] = run; run += x; }
    }
}

__global__ __launch_bounds__(256) void scan_add(int* __restrict__ ptrv,
                                                const int* __restrict__ bsum,
                                                int* __restrict__ cnt,
                                                float* __restrict__ dinv) {
    int i = blockIdx.x * 256 + threadIdx.x;
    if (i < N_NODES) {
        int c = cnt[i];
        dinv[i] = rsqrtf((float)(c + 1));
        ptrv[i] += bsum[i >> 10];
        cnt[i] = 0;
    }
    if (i == 0) ptrv[N_NODES] = NE;
}

// scatter only src index (weight recomputed on the fly in propagate)
__global__ __launch_bounds__(256) void fill_csr(const int* __restrict__ rowp,
                                                const int* __restrict__ colp,
                                                const int* __restrict__ ptrv,
                                                int* __restrict__ cnt,
                                                int* __restrict__ src) {
    int e = blockIdx.x * 256 + threadIdx.x;
    if (e < NE) {
        int c = colp[e];
        int pos = ptrv[c] + atomicAdd(&cnt[c], 1);
        src[pos] = rowp[e];
    }
}

// ---------------------------------------------------------------------------
// casts
// ---------------------------------------------------------------------------
__global__ __launch_bounds__(256) void xcast(const float* __restrict__ x,
                                             unsigned* __restrict__ Xh) {
    int idx = blockIdx.x * 256 + threadIdx.x;      // over NPAD*64 uints
    if (idx >= NPAD * 64) return;
    int e = idx * 2;
    float a = (e     < N_NODES * DIM) ? x[e]     : 0.f;
    float b = (e + 1 < N_NODES * DIM) ? x[e + 1] : 0.f;
    Xh[idx] = pk2(a, b);
}

// Wt[g][i][n][k] = (half) W_g[i][k][n]
__global__ __launch_bounds__(256) void wcast(const float* __restrict__ Wo,
                                             const float* __restrict__ Wa,
                                             unsigned short* __restrict__ Wt) {
    int idx = blockIdx.x * 256 + threadIdx.x;
    if (idx >= 2 * 5 * DIM * DIM) return;
    int g   = idx / (5 * DIM * DIM);
    int rem = idx % (5 * DIM * DIM);
    int i   = rem / (DIM * DIM);
    int nk  = rem % (DIM * DIM);
    int n = nk / DIM, k = nk % DIM;
    const float* W = g ? Wa : Wo;
    Wt[idx] = f2hbits(W[i * DIM * DIM + k * DIM + n]);
}

// ---------------------------------------------------------------------------
// Propagation in fp16 storage / fp32 math. One wave per node, 4 B (2 halves)
// per lane -> each edge gather = 256 B coalesced.
// ---------------------------------------------------------------------------
__global__ __launch_bounds__(256) void propagate(const unsigned* __restrict__ Tin,
                                                 unsigned* __restrict__ Tout,
                                                 const int* __restrict__ ptrv,
                                                 const int* __restrict__ src,
                                                 const float* __restrict__ dinv) {
    int gid  = blockIdx.x * 256 + threadIdx.x;
    int v    = gid >> 6;
    int lane = threadIdx.x & 63;
    if (v >= N_NODES) return;
    float dv = dinv[v];
    float2 self = up2(Tin[v * 64 + lane]);
    float ax = dv * dv * self.x;
    float ay = dv * dv * self.y;
    int beg = ptrv[v], end = ptrv[v + 1];
    int k = beg;
    int n4 = beg + ((end - beg) & ~3);
    for (; k < n4; k += 4) {
        int u0 = src[k], u1 = src[k + 1], u2 = src[k + 2], u3 = src[k + 3];
        float w0 = dinv[u0] * dv, w1 = dinv[u1] * dv;
        float w2 = dinv[u2] * dv, w3 = dinv[u3] * dv;
        float2 t0 = up2(Tin[u0 * 64 + lane]);
        float2 t1 = up2(Tin[u1 * 64 + lane]);
        float2 t2 = up2(Tin[u2 * 64 + lane]);
        float2 t3 = up2(Tin[u3 * 64 + lane]);
        ax += w0 * t0.x; ay += w0 * t0.y;
        ax += w1 * t1.x; ay += w1 * t1.y;
        ax += w2 * t2.x; ay += w2 * t2.y;
        ax += w3 * t3.x; ay += w3 * t3.y;
    }
    for (; k < end; ++k) {
        int u = src[k];
        float w = dinv[u] * dv;
        float2 t = up2(Tin[u * 64 + lane]);
        ax += w * t.x; ay += w * t.y;
    }
    Tout[v * 64 + lane] = pk2(ax, ay);
}

// ---------------------------------------------------------------------------
// acc[m][n] = sum_i T_i[m][:] @ W_i[:][n]  via fp16 MFMA, fp32 accumulate.
// block = 4 waves = 64 rows; each wave: 16 rows x 128 cols (8 MFMA tiles).
// A-frag: A[m=lane&15][k=q*8+j] ; B-frag from Wt[n][k] (transposed) same shape.
// C/D: row = q*4+reg, col = lane&15.
// ---------------------------------------------------------------------------
__global__ __launch_bounds__(256) void gemm5(const unsigned short* __restrict__ T0,
                                             const unsigned short* __restrict__ T1,
                                             const unsigned short* __restrict__ T2,
                                             const unsigned short* __restrict__ T3,
                                             const unsigned short* __restrict__ T4,
                                             const unsigned short* __restrict__ Wt,
                                             float* __restrict__ C) {
    const unsigned short* Ts[5] = {T0, T1, T2, T3, T4};
    int t = threadIdx.x;
    int lane = t & 63, wv = t >> 6;
    int m0 = blockIdx.x * 64 + wv * 16;
    int l15 = lane & 15, q = lane >> 4;
    f4 acc[8];
#pragma unroll
    for (int n = 0; n < 8; ++n) acc[n] = (f4)(0.f);
#pragma unroll
    for (int i = 0; i < 5; ++i) {
        const unsigned short* A = Ts[i] + (size_t)(m0 + l15) * DIM + q * 8;
        const unsigned short* B = Wt + (size_t)i * DIM * DIM + (size_t)l15 * DIM + q * 8;
#pragma unroll
        for (int k0 = 0; k0 < DIM; k0 += 32) {
            h8 af = *(const h8*)(A + k0);
#pragma unroll
            for (int n = 0; n < 8; ++n) {
                h8 bf = *(const h8*)(B + n * 16 * DIM + k0);
                acc[n] = __builtin_amdgcn_mfma_f32_16x16x32_f16(af, bf, acc[n], 0, 0, 0);
            }
        }
    }
    float* Cw = C + (size_t)(m0 + q * 4) * DIM + l15;
#pragma unroll
    for (int n = 0; n < 8; ++n)
#pragma unroll
        for (int r = 0; r < 4; ++r)
            Cw[(size_t)r * DIM + n * 16] = acc[n][r];
}

// ---------------------------------------------------------------------------
// out = (w0*relu(accO + sum bO) + w1*relu(accA + sum bA)) @ clfW + clfB
// ---------------------------------------------------------------------------
__global__ __launch_bounds__(256) void fuse_clf(const float* __restrict__ accO,
                                                const float* __restrict__ accA,
                                                const float* __restrict__ bO,
                                                const float* __restrict__ bA,
                                                const float* __restrict__ fw,
                                                const float* __restrict__ clfW,
                                                const float* __restrict__ clfB,
                                                float* __restrict__ out) {
    __shared__ float Wl[DIM * ODIM];
    __shared__ float Hl[32 * DIM];
    __shared__ float bs[2][DIM];
    int t = threadIdx.x;
    float f0 = fw[0], f1 = fw[1];
    float m = fmaxf(f0, f1);
    float e0 = expf(f0 - m), e1 = expf(f1 - m);
    float sw0 = e0 / (e0 + e1), sw1 = e1 / (e0 + e1);
    if (t < 128) {
        float s = 0.f;
        for (int i = 0; i <= NORDER; ++i) s += bO[i * DIM + t];
        bs[0][t] = s;
    } else {
        int j = t - 128;
        float s = 0.f;
        for (int i = 0; i <= NORDER; ++i) s += bA[i * DIM + j];
        bs[1][j] = s;
    }
    for (int i = 0; i < 8; ++i) {
        int idx = (i * 256 + t) * 4;
        *(float4*)&Wl[idx] = *(const float4*)&clfW[idx];
    }
    __syncthreads();
    int rowBase = blockIdx.x * 32;
    for (int i = 0; i < 4; ++i) {
        int idx = (i * 256 + t) * 4;
        int kcol = idx & 127;
        float4 a = *(const float4*)&accO[rowBase * DIM + idx];
        float4 b = *(const float4*)&accA[rowBase * DIM + idx];
        float4 h;
        h.x = sw0 * fmaxf(a.x + bs[0][kcol + 0], 0.f) + sw1 * fmaxf(b.x + bs[1][kcol + 0], 0.f);
        h.y = sw0 * fmaxf(a.y + bs[0][kcol + 1], 0.f) + sw1 * fmaxf(b.y + bs[1][kcol + 1], 0.f);
        h.z = sw0 * fmaxf(a.z + bs[0][kcol + 2], 0.f) + sw1 * fmaxf(b.z + bs[1][kcol + 2], 0.f);
        h.w = sw0 * fmaxf(a.w + bs[0][kcol + 3], 0.f) + sw1 * fmaxf(b.w + bs[1][kcol + 3], 0.f);
        *(float4*)&Hl[idx] = h;
    }
    __syncthreads();
    int lane = t & 63, w = t >> 6;
    int c2 = (lane & 31) * 2;
    int r0 = w * 8 + (lane >> 5) * 4;
    float acc[4][2];
    for (int j = 0; j < 4; ++j) { acc[j][0] = 0.f; acc[j][1] = 0.f; }
    for (int k0 = 0; k0 < DIM; k0 += 4) {
        float4 a0 = *(const float4*)&Hl[(r0 + 0) * DIM + k0];
        float4 a1 = *(const float4*)&Hl[(r0 + 1) * DIM + k0];
        float4 a2 = *(const float4*)&Hl[(r0 + 2) * DIM + k0];
        float4 a3 = *(const float4*)&Hl[(r0 + 3) * DIM + k0];
#define FSTEP(comp, kk)                                                      \
        {                                                                    \
            float2 wv = *(const float2*)&Wl[(k0 + kk) * ODIM + c2];          \
            acc[0][0] += a0.comp * wv.x; acc[0][1] += a0.comp * wv.y;        \
            acc[1][0] += a1.comp * wv.x; acc[1][1] += a1.comp * wv.y;        \
            acc[2][0] += a2.comp * wv.x; acc[2][1] += a2.comp * wv.y;        \
            acc[3][0] += a3.comp * wv.x; acc[3][1] += a3.comp * wv.y;        \
        }
        FSTEP(x, 0) FSTEP(y, 1) FSTEP(z, 2) FSTEP(w, 3)
#undef FSTEP
    }
    float2 cb2 = *(const float2*)&clfB[c2];
    for (int j = 0; j < 4; ++j) {
        float2 o = make_float2(acc[j][0] + cb2.x, acc[j][1] + cb2.y);
        *(float2*)&out[(rowBase + r0 + j) * ODIM + c2] = o;
    }
}

// ---------------------------------------------------------------------------
extern "C" void kernel_launch(void* const* d_in, const int* in_sizes, int n_in,
                              void* d_out, int out_size, void* d_ws, size_t ws_size,
                              hipStream_t stream) {
    const float* x   = (const float*)d_in[0];
    const int*   ei  = (const int*)d_in[1];
    const int*   gi  = (const int*)d_in[2];
    const float* w_o = (const float*)d_in[3];
    const float* b_o = (const float*)d_in[4];
    const float* w_a = (const float*)d_in[5];
    const float* b_a = (const float*)d_in[6];
    const float* fw  = (const float*)d_in[7];
    const float* cw  = (const float*)d_in[8];
    const float* cb  = (const float*)d_in[9];
    float* out = (float*)d_out;

    char* p = (char*)d_ws;
    auto alloc = [&](size_t bytes) {
        void* r = (void*)p;
        p += (bytes + 255) & ~(size_t)255;
        return r;
    };
    unsigned* Xh = (unsigned*)alloc((size_t)NPAD * 64 * 4);      // fp16 x, packed
    unsigned* T1 = (unsigned*)alloc((size_t)NPAD * 64 * 4);
    unsigned* T2 = (unsigned*)alloc((size_t)NPAD * 64 * 4);
    unsigned* T3 = (unsigned*)alloc((size_t)NPAD * 64 * 4);
    unsigned* T4 = (unsigned*)alloc((size_t)NPAD * 64 * 4);
    float* acc_o = (float*)alloc((size_t)NPAD * DIM * 4);
    float* acc_a = (float*)alloc((size_t)NPAD * DIM * 4);
    unsigned short* Wt = (unsigned short*)alloc((size_t)2 * 5 * DIM * DIM * 2);
    float* dinv    = (float*)alloc((size_t)N_NODES * 4);
    int*   csr_src = (int*)alloc((size_t)NE * 4);
    int*   csr_ptr = (int*)alloc((size_t)(N_NODES + 1) * 4);
    int*   cnt     = (int*)alloc((size_t)N_NODES * 4);
    int*   bsum    = (int*)alloc(128 * 4);

    const int gN  = (N_NODES + 255) / 256;        // 391
    const int gE  = (NE + 255) / 256;             // 6250
    const int gS  = (N_NODES + 1023) / 1024;      // 98
    const int gP  = (N_NODES * 64 + 255) / 256;   // 25000
    const int gX  = (NPAD * 64 + 255) / 256;      // 25008
    const int gW  = (2 * 5 * DIM * DIM + 255) / 256;
    const int gM  = NPAD / 64;                    // 1563
    const int gF  = N_NODES / 32;                 // 3125

    xcast<<<gX, 256, 0, stream>>>(x, Xh);
    wcast<<<gW, 256, 0, stream>>>(w_o, w_a, Wt);

    unsigned* Ts[5] = {Xh, T1, T2, T3, T4};
    for (int g = 0; g < 2; ++g) {
        const int* edges = g ? gi : ei;
        const int* rowp = edges;
        const int* colp = edges + NE;
        float* acc = g ? acc_a : acc_o;
        const unsigned short* Wtg = Wt + (size_t)g * 5 * DIM * DIM;

        zero_cnt<<<gN, 256, 0, stream>>>(cnt);
        count_edges<<<gE, 256, 0, stream>>>(colp, cnt);
        scan_block<<<gS, 256, 0, stream>>>(cnt, csr_ptr, bsum);
        scan_mid<<<1, 64, 0, stream>>>(bsum, gS);
        scan_add<<<gN, 256, 0, stream>>>(csr_ptr, bsum, cnt, dinv);
        fill_csr<<<gE, 256, 0, stream>>>(rowp, colp, csr_ptr, cnt, csr_src);

        for (int i = 1; i <= NORDER; ++i)
            propagate<<<gP, 256, 0, stream>>>(Ts[i - 1], Ts[i], csr_ptr, csr_src, dinv);

        gemm5<<<gM, 256, 0, stream>>>((const unsigned short*)Xh,
                                      (const unsigned short*)T1,
                                      (const unsigned short*)T2,
                                      (const unsigned short*)T3,
                                      (const unsigned short*)T4,
                                      Wtg, acc);
    }
    fuse_clf<<<gF, 256, 0, stream>>>(acc_o, acc_a, b_o, b_a, fw, cw, cb, out);
}

// Round 4
// 1172.435 us; speedup vs baseline: 1.6971x; 1.1419x over previous
//
#include <hip/hip_runtime.h>

#define N_NODES 100000
#define NPAD    100096      // multiple of 128 for GEMM tiles
#define NE      1600000
#define DIM     128
#define ODIM    64
#define NORDER  4
#define KTOT    640         // 5 * 128, T stored as one M x 640 matrix

typedef _Float16 h8 __attribute__((ext_vector_type(8)));
typedef float f4 __attribute__((ext_vector_type(4)));

__device__ __forceinline__ float2 up2(unsigned p) {
    union { unsigned u; _Float16 h[2]; } c; c.u = p;
    return make_float2((float)c.h[0], (float)c.h[1]);
}
__device__ __forceinline__ unsigned pk2(float x, float y) {
    union { unsigned u; _Float16 h[2]; } c;
    c.h[0] = (_Float16)x; c.h[1] = (_Float16)y;
    return c.u;
}
__device__ __forceinline__ unsigned short f2hbits(float x) {
    union { _Float16 h; unsigned short s; } c;
    c.h = (_Float16)x;
    return c.s;
}
__device__ __forceinline__ void async_cp16(const void* g, void* l) {
    __builtin_amdgcn_global_load_lds((const __attribute__((address_space(1))) void*)g,
                                     (__attribute__((address_space(3))) void*)l, 16, 0, 0);
}

// ---------------------------------------------------------------------------
// CSR build
// ---------------------------------------------------------------------------
__global__ __launch_bounds__(256) void zero_cnt(int* __restrict__ cnt) {
    int i = blockIdx.x * 256 + threadIdx.x;
    if (i < N_NODES) cnt[i] = 0;
}

__global__ __launch_bounds__(256) void count_edges(const int* __restrict__ colp,
                                                   int* __restrict__ cnt) {
    int e = (blockIdx.x * 256 + threadIdx.x) * 4;
    if (e + 3 < NE) {
        int4 c = *(const int4*)&colp[e];
        atomicAdd(&cnt[c.x], 1);
        atomicAdd(&cnt[c.y], 1);
        atomicAdd(&cnt[c.z], 1);
        atomicAdd(&cnt[c.w], 1);
    } else {
        for (int j = e; j < NE; ++j) atomicAdd(&cnt[colp[j]], 1);
    }
}

__global__ __launch_bounds__(256) void scan_block(const int* __restrict__ cnt,
                                                  int* __restrict__ excl,
                                                  int* __restrict__ bsum) {
    __shared__ int lds[256];
    int t = threadIdx.x, b = blockIdx.x;
    int base = b * 1024 + t * 4;
    int v0 = (base + 0 < N_NODES) ? cnt[base + 0] : 0;
    int v1 = (base + 1 < N_NODES) ? cnt[base + 1] : 0;
    int v2 = (base + 2 < N_NODES) ? cnt[base + 2] : 0;
    int v3 = (base + 3 < N_NODES) ? cnt[base + 3] : 0;
    int tot = v0 + v1 + v2 + v3;
    lds[t] = tot;
    __syncthreads();
    for (int off = 1; off < 256; off <<= 1) {
        int x = (t >= off) ? lds[t - off] : 0;
        __syncthreads();
        lds[t] += x;
        __syncthreads();
    }
    int run = lds[t] - tot;
    if (t == 255) bsum[b] = lds[255];
    if (base + 0 < N_NODES) excl[base + 0] = run; run += v0;
    if (base + 1 < N_NODES) excl[base + 1] = run; run += v1;
    if (base + 2 < N_NODES) excl[base + 2] = run; run += v2;
    if (base + 3 < N_NODES) excl[base + 3] = run;
}

__global__ void scan_mid(int* __restrict__ bsum, int nb) {
    if (threadIdx.x == 0 && blockIdx.x == 0) {
        int run = 0;
        for (int i = 0; i < nb; ++i) { int x = bsum[i]; bsum[i] = run; run += x; }
    }
}

__global__ __launch_bounds__(256) void scan_add(int* __restrict__ ptrv,
                                                const int* __restrict__ bsum,
                                                int* __restrict__ cnt,
                                                float* __restrict__ dinv) {
    int i = blockIdx.x * 256 + threadIdx.x;
    if (i < N_NODES) {
        int c = cnt[i];
        dinv[i] = rsqrtf((float)(c + 1));
        ptrv[i] += bsum[i >> 10];
        cnt[i] = 0;
    }
    if (i == 0) ptrv[N_NODES] = NE;
}

// scatter (src, weight) as one 8 B pair per edge
__global__ __launch_bounds__(256) void fill_csr(const int* __restrict__ rowp,
                                                const int* __restrict__ colp,
                                                const int* __restrict__ ptrv,
                                                int* __restrict__ cnt,
                                                int2* __restrict__ pairs,
                                                const float* __restrict__ dinv) {
    int e = blockIdx.x * 256 + threadIdx.x;
    if (e < NE) {
        int c = colp[e];
        int r = rowp[e];
        int pos = ptrv[c] + atomicAdd(&cnt[c], 1);
        pairs[pos] = make_int2(r, __float_as_int(dinv[r] * dinv[c]));
    }
}

// ---------------------------------------------------------------------------
// casts
// ---------------------------------------------------------------------------
// x -> slice 0 of Tbig [NPAD][640] fp16 (row stride 320 uints)
__global__ __launch_bounds__(256) void xcast(const float* __restrict__ x,
                                             unsigned* __restrict__ Tbig) {
    int idx = blockIdx.x * 256 + threadIdx.x;
    if (idx >= NPAD * 64) return;
    int m = idx >> 6, u = idx & 63;
    int e = (m << 7) + u * 2;
    float a = (m < N_NODES) ? x[e]     : 0.f;
    float b = (m < N_NODES) ? x[e + 1] : 0.f;
    Tbig[m * 320 + u] = pk2(a, b);
}

// Wt[g][i][k8][n][k7] = (half) W_g[i][k8*8+k7][n]   (chunk-transposed for LDS)
__global__ __launch_bounds__(256) void wcast(const float* __restrict__ Wo,
                                             const float* __restrict__ Wa,
                                             unsigned short* __restrict__ Wt) {
    int idx = blockIdx.x * 256 + threadIdx.x;
    if (idx >= 2 * 5 * DIM * DIM) return;
    int g   = idx / (5 * DIM * DIM);
    int rem = idx % (5 * DIM * DIM);
    int i   = rem / (DIM * DIM);
    int r2  = rem % (DIM * DIM);
    int k8  = r2 >> 10;
    int n   = (r2 >> 3) & 127;
    int k7  = r2 & 7;
    int k   = k8 * 8 + k7;
    const float* W = g ? Wa : Wo;
    Wt[idx] = f2hbits(W[(i * DIM + k) * DIM + n]);
}

// ---------------------------------------------------------------------------
// Propagation: one wave per node; Tin/Tout are slice base pointers into Tbig
// (row stride 320 uints). (src, w) packed pairs; 8-deep gather pipeline.
// ---------------------------------------------------------------------------
__global__ __launch_bounds__(256) void propagate(const unsigned* __restrict__ Tin,
                                                 unsigned* __restrict__ Tout,
                                                 const int* __restrict__ ptrv,
                                                 const int2* __restrict__ pairs,
                                                 const float* __restrict__ dinv) {
    int gid  = blockIdx.x * 256 + threadIdx.x;
    int v    = gid >> 6;
    int lane = threadIdx.x & 63;
    if (v >= N_NODES) return;
    float dv = dinv[v];
    float2 self = up2(Tin[v * 320 + lane]);
    float ax = dv * dv * self.x;
    float ay = dv * dv * self.y;
    int beg = ptrv[v], end = ptrv[v + 1];
    int k = beg;
    int n8 = beg + ((end - beg) & ~7);
    for (; k < n8; k += 8) {
        int2 p0 = pairs[k + 0], p1 = pairs[k + 1], p2 = pairs[k + 2], p3 = pairs[k + 3];
        int2 p4 = pairs[k + 4], p5 = pairs[k + 5], p6 = pairs[k + 6], p7 = pairs[k + 7];
        float2 t0 = up2(Tin[p0.x * 320 + lane]);
        float2 t1 = up2(Tin[p1.x * 320 + lane]);
        float2 t2 = up2(Tin[p2.x * 320 + lane]);
        float2 t3 = up2(Tin[p3.x * 320 + lane]);
        float2 t4 = up2(Tin[p4.x * 320 + lane]);
        float2 t5 = up2(Tin[p5.x * 320 + lane]);
        float2 t6 = up2(Tin[p6.x * 320 + lane]);
        float2 t7 = up2(Tin[p7.x * 320 + lane]);
        float w0 = __int_as_float(p0.y), w1 = __int_as_float(p1.y);
        float w2 = __int_as_float(p2.y), w3 = __int_as_float(p3.y);
        float w4 = __int_as_float(p4.y), w5 = __int_as_float(p5.y);
        float w6 = __int_as_float(p6.y), w7 = __int_as_float(p7.y);
        ax += w0 * t0.x; ay += w0 * t0.y;
        ax += w1 * t1.x; ay += w1 * t1.y;
        ax += w2 * t2.x; ay += w2 * t2.y;
        ax += w3 * t3.x; ay += w3 * t3.y;
        ax += w4 * t4.x; ay += w4 * t4.y;
        ax += w5 * t5.x; ay += w5 * t5.y;
        ax += w6 * t6.x; ay += w6 * t6.y;
        ax += w7 * t7.x; ay += w7 * t7.y;
    }
    for (; k < end; ++k) {
        int2 p = pairs[k];
        float w = __int_as_float(p.y);
        float2 t = up2(Tin[p.x * 320 + lane]);
        ax += w * t.x; ay += w * t.y;
    }
    Tout[v * 320 + lane] = pk2(ax, ay);
}

// ---------------------------------------------------------------------------
// C[M x 128] = A[M x 640] @ W[640 x 128] via fp16 MFMA.
// Block: 256 thr / 4 waves, BM = 128 (32 rows per wave), all 128 cols.
// Per order i: B_i (32 KB, chunk-transposed [k8][n][8]) staged to LDS via
// global_load_lds (PER-LANE global addr + wave-uniform LDS base!);
// A-frags prefetched into regs before the staging barrier.
// ---------------------------------------------------------------------------
__global__ __launch_bounds__(256, 3) void gemmK(const unsigned short* __restrict__ A,
                                                const unsigned short* __restrict__ Wt,
                                                float* __restrict__ C) {
    __shared__ unsigned short Bl[DIM * DIM];   // 32 KB
    int t = threadIdx.x;
    int lane = t & 63, wv = t >> 6;
    int m0 = blockIdx.x * 128 + wv * 32;
    int l15 = lane & 15, q = lane >> 4;
    f4 acc[2][8];
#pragma unroll
    for (int mt = 0; mt < 2; ++mt)
#pragma unroll
        for (int nt = 0; nt < 8; ++nt) acc[mt][nt] = (f4)(0.f);

#pragma unroll
    for (int i = 0; i < 5; ++i) {
        const unsigned short* WtI = Wt + (size_t)i * DIM * DIM;
        // A-frag prefetch (latency drains together with the async staging)
        h8 af[2][4];
#pragma unroll
        for (int mt = 0; mt < 2; ++mt)
#pragma unroll
            for (int kc = 0; kc < 4; ++kc)
                af[mt][kc] = *(const h8*)(A + (size_t)(m0 + mt * 16 + l15) * KTOT
                                            + i * DIM + (kc * 4 + q) * 8);
        // stage B_i: 32 chunks x 1 KB; lane supplies its own 16 B slice,
        // HW scatters to (uniform LDS base) + lane*16
#pragma unroll
        for (int c = 0; c < 8; ++c) {
            int ci = c * 4 + wv;
            async_cp16(WtI + ci * 512 + lane * 8, &Bl[ci * 512]);
        }
        __syncthreads();
#pragma unroll
        for (int kc = 0; kc < 4; ++kc) {
            int c = kc * 4 + q;
#pragma unroll
            for (int nt = 0; nt < 8; ++nt) {
                h8 bf = *(const h8*)&Bl[(size_t)(c * 128 + nt * 16 + l15) * 8];
                acc[0][nt] = __builtin_amdgcn_mfma_f32_16x16x32_f16(af[0][kc], bf, acc[0][nt], 0, 0, 0);
                acc[1][nt] = __builtin_amdgcn_mfma_f32_16x16x32_f16(af[1][kc], bf, acc[1][nt], 0, 0, 0);
            }
        }
        __syncthreads();
    }
#pragma unroll
    for (int mt = 0; mt < 2; ++mt)
#pragma unroll
        for (int nt = 0; nt < 8; ++nt)
#pragma unroll
            for (int r = 0; r < 4; ++r)
                C[(size_t)(m0 + mt * 16 + q * 4 + r) * DIM + nt * 16 + l15] = acc[mt][nt][r];
}

// ---------------------------------------------------------------------------
// out = (w0*relu(accO + sum bO) + w1*relu(accA + sum bA)) @ clfW + clfB
// ---------------------------------------------------------------------------
__global__ __launch_bounds__(256) void fuse_clf(const float* __restrict__ accO,
                                                const float* __restrict__ accA,
                                                const float* __restrict__ bO,
                                                const float* __restrict__ bA,
                                                const float* __restrict__ fw,
                                                const float* __restrict__ clfW,
                                                const float* __restrict__ clfB,
                                                float* __restrict__ out) {
    __shared__ float Wl[DIM * ODIM];
    __shared__ float Hl[32 * DIM];
    __shared__ float bs[2][DIM];
    int t = threadIdx.x;
    float f0 = fw[0], f1 = fw[1];
    float m = fmaxf(f0, f1);
    float e0 = expf(f0 - m), e1 = expf(f1 - m);
    float sw0 = e0 / (e0 + e1), sw1 = e1 / (e0 + e1);
    if (t < 128) {
        float s = 0.f;
        for (int i = 0; i <= NORDER; ++i) s += bO[i * DIM + t];
        bs[0][t] = s;
    } else {
        int j = t - 128;
        float s = 0.f;
        for (int i = 0; i <= NORDER; ++i) s += bA[i * DIM + j];
        bs[1][j] = s;
    }
    for (int i = 0; i < 8; ++i) {
        int idx = (i * 256 + t) * 4;
        *(float4*)&Wl[idx] = *(const float4*)&clfW[idx];
    }
    __syncthreads();
    int rowBase = blockIdx.x * 32;
    for (int i = 0; i < 4; ++i) {
        int idx = (i * 256 + t) * 4;
        int kcol = idx & 127;
        float4 a = *(const float4*)&accO[rowBase * DIM + idx];
        float4 b = *(const float4*)&accA[rowBase * DIM + idx];
        float4 h;
        h.x = sw0 * fmaxf(a.x + bs[0][kcol + 0], 0.f) + sw1 * fmaxf(b.x + bs[1][kcol + 0], 0.f);
        h.y = sw0 * fmaxf(a.y + bs[0][kcol + 1], 0.f) + sw1 * fmaxf(b.y + bs[1][kcol + 1], 0.f);
        h.z = sw0 * fmaxf(a.z + bs[0][kcol + 2], 0.f) + sw1 * fmaxf(b.z + bs[1][kcol + 2], 0.f);
        h.w = sw0 * fmaxf(a.w + bs[0][kcol + 3], 0.f) + sw1 * fmaxf(b.w + bs[1][kcol + 3], 0.f);
        *(float4*)&Hl[idx] = h;
    }
    __syncthreads();
    int lane = t & 63, w = t >> 6;
    int c2 = (lane & 31) * 2;
    int r0 = w * 8 + (lane >> 5) * 4;
    float acc[4][2];
    for (int j = 0; j < 4; ++j) { acc[j][0] = 0.f; acc[j][1] = 0.f; }
    for (int k0 = 0; k0 < DIM; k0 += 4) {
        float4 a0 = *(const float4*)&Hl[(r0 + 0) * DIM + k0];
        float4 a1 = *(const float4*)&Hl[(r0 + 1) * DIM + k0];
        float4 a2 = *(const float4*)&Hl[(r0 + 2) * DIM + k0];
        float4 a3 = *(const float4*)&Hl[(r0 + 3) * DIM + k0];
#define FSTEP(comp, kk)                                                      \
        {                                                                    \
            float2 wv = *(const float2*)&Wl[(k0 + kk) * ODIM + c2];          \
            acc[0][0] += a0.comp * wv.x; acc[0][1] += a0.comp * wv.y;        \
            acc[1][0] += a1.comp * wv.x; acc[1][1] += a1.comp * wv.y;        \
            acc[2][0] += a2.comp * wv.x; acc[2][1] += a2.comp * wv.y;        \
            acc[3][0] += a3.comp * wv.x; acc[3][1] += a3.comp * wv.y;        \
        }
        FSTEP(x, 0) FSTEP(y, 1) FSTEP(z, 2) FSTEP(w, 3)
#undef FSTEP
    }
    float2 cb2 = *(const float2*)&clfB[c2];
    for (int j = 0; j < 4; ++j) {
        float2 o = make_float2(acc[j][0] + cb2.x, acc[j][1] + cb2.y);
        *(float2*)&out[(rowBase + r0 + j) * ODIM + c2] = o;
    }
}

// ---------------------------------------------------------------------------
extern "C" void kernel_launch(void* const* d_in, const int* in_sizes, int n_in,
                              void* d_out, int out_size, void* d_ws, size_t ws_size,
                              hipStream_t stream) {
    const float* x   = (const float*)d_in[0];
    const int*   ei  = (const int*)d_in[1];
    const int*   gi  = (const int*)d_in[2];
    const float* w_o = (const float*)d_in[3];
    const float* b_o = (const float*)d_in[4];
    const float* w_a = (const float*)d_in[5];
    const float* b_a = (const float*)d_in[6];
    const float* fw  = (const float*)d_in[7];
    const float* cw  = (const float*)d_in[8];
    const float* cb  = (const float*)d_in[9];
    float* out = (float*)d_out;

    char* p = (char*)d_ws;
    auto alloc = [&](size_t bytes) {
        void* r = (void*)p;
        p += (bytes + 255) & ~(size_t)255;
        return r;
    };
    unsigned* Tbig = (unsigned*)alloc((size_t)NPAD * 320 * 4);        // [NPAD][640] fp16
    float* acc_o = (float*)alloc((size_t)NPAD * DIM * 4);
    float* acc_a = (float*)alloc((size_t)NPAD * DIM * 4);
    unsigned short* Wt = (unsigned short*)alloc((size_t)2 * 5 * DIM * DIM * 2);
    float* dinv  = (float*)alloc((size_t)N_NODES * 4);
    int2* pairs  = (int2*)alloc((size_t)NE * 8);
    int* csr_ptr = (int*)alloc((size_t)(N_NODES + 1) * 4);
    int* cnt     = (int*)alloc((size_t)N_NODES * 4);
    int* bsum    = (int*)alloc(128 * 4);

    const int gN  = (N_NODES + 255) / 256;          // 391
    const int gE  = (NE + 255) / 256;               // 6250
    const int gE4 = (NE / 4 + 255) / 256;           // 1563
    const int gS  = (N_NODES + 1023) / 1024;        // 98
    const int gP  = (N_NODES * 64 + 255) / 256;     // 25000
    const int gX  = (NPAD * 64 + 255) / 256;        // 25024
    const int gW  = (2 * 5 * DIM * DIM + 255) / 256;
    const int gM  = NPAD / 128;                     // 782
    const int gF  = N_NODES / 32;                   // 3125

    xcast<<<gX, 256, 0, stream>>>(x, Tbig);
    wcast<<<gW, 256, 0, stream>>>(w_o, w_a, Wt);

    for (int g = 0; g < 2; ++g) {
        const int* edges = g ? gi : ei;
        const int* rowp = edges;
        const int* colp = edges + NE;
        float* acc = g ? acc_a : acc_o;
        const unsigned short* Wtg = Wt + (size_t)g * 5 * DIM * DIM;

        zero_cnt<<<gN, 256, 0, stream>>>(cnt);
        count_edges<<<gE4, 256, 0, stream>>>(colp, cnt);
        scan_block<<<gS, 256, 0, stream>>>(cnt, csr_ptr, bsum);
        scan_mid<<<1, 64, 0, stream>>>(bsum, gS);
        scan_add<<<gN, 256, 0, stream>>>(csr_ptr, bsum, cnt, dinv);
        fill_csr<<<gE, 256, 0, stream>>>(rowp, colp, csr_ptr, cnt, pairs, dinv);

        for (int i = 1; i <= NORDER; ++i)
            propagate<<<gP, 256, 0, stream>>>(Tbig + (i - 1) * 64, Tbig + i * 64,
                                              csr_ptr, pairs, dinv);

        gemmK<<<gM, 256, 0, stream>>>((const unsigned short*)Tbig, Wtg, acc);
    }
    fuse_clf<<<gF, 256, 0, stream>>>(acc_o, acc_a, b_o, b_a, fw, cw, cb, out);
}

// Round 5
// 1057.614 us; speedup vs baseline: 1.8814x; 1.1086x over previous
//
#include <hip/hip_runtime.h>

#define N_NODES 100000
#define NPAD    100096      // multiple of 128 for GEMM tiles
#define NE      1600000
#define DIM     128
#define ODIM    64
#define NORDER  4
#define KTOT    640         // 5 * 128, T stored as one M x 640 matrix

typedef _Float16 h8 __attribute__((ext_vector_type(8)));
typedef float f4 __attribute__((ext_vector_type(4)));

__device__ __forceinline__ float2 up2(unsigned p) {
    union { unsigned u; _Float16 h[2]; } c; c.u = p;
    return make_float2((float)c.h[0], (float)c.h[1]);
}
__device__ __forceinline__ unsigned pk2(float x, float y) {
    union { unsigned u; _Float16 h[2]; } c;
    c.h[0] = (_Float16)x; c.h[1] = (_Float16)y;
    return c.u;
}
__device__ __forceinline__ unsigned short f2hbits(float x) {
    union { _Float16 h; unsigned short s; } c;
    c.h = (_Float16)x;
    return c.s;
}
__device__ __forceinline__ void async_cp16(const void* g, void* l) {
    __builtin_amdgcn_global_load_lds((const __attribute__((address_space(1))) void*)g,
                                     (__attribute__((address_space(3))) void*)l, 16, 0, 0);
}

// ---------------------------------------------------------------------------
// CSR build
// ---------------------------------------------------------------------------
__global__ __launch_bounds__(256) void zero_cnt(int* __restrict__ cnt) {
    int i = blockIdx.x * 256 + threadIdx.x;
    if (i < N_NODES) cnt[i] = 0;
}

__global__ __launch_bounds__(256) void count_edges(const int* __restrict__ colp,
                                                   int* __restrict__ cnt) {
    int e = (blockIdx.x * 256 + threadIdx.x) * 4;
    if (e + 3 < NE) {
        int4 c = *(const int4*)&colp[e];
        atomicAdd(&cnt[c.x], 1);
        atomicAdd(&cnt[c.y], 1);
        atomicAdd(&cnt[c.z], 1);
        atomicAdd(&cnt[c.w], 1);
    } else {
        for (int j = e; j < NE; ++j) atomicAdd(&cnt[colp[j]], 1);
    }
}

__global__ __launch_bounds__(256) void scan_block(const int* __restrict__ cnt,
                                                  int* __restrict__ excl,
                                                  int* __restrict__ bsum) {
    __shared__ int lds[256];
    int t = threadIdx.x, b = blockIdx.x;
    int base = b * 1024 + t * 4;
    int v0 = (base + 0 < N_NODES) ? cnt[base + 0] : 0;
    int v1 = (base + 1 < N_NODES) ? cnt[base + 1] : 0;
    int v2 = (base + 2 < N_NODES) ? cnt[base + 2] : 0;
    int v3 = (base + 3 < N_NODES) ? cnt[base + 3] : 0;
    int tot = v0 + v1 + v2 + v3;
    lds[t] = tot;
    __syncthreads();
    for (int off = 1; off < 256; off <<= 1) {
        int x = (t >= off) ? lds[t - off] : 0;
        __syncthreads();
        lds[t] += x;
        __syncthreads();
    }
    int run = lds[t] - tot;
    if (t == 255) bsum[b] = lds[255];
    if (base + 0 < N_NODES) excl[base + 0] = run; run += v0;
    if (base + 1 < N_NODES) excl[base + 1] = run; run += v1;
    if (base + 2 < N_NODES) excl[base + 2] = run; run += v2;
    if (base + 3 < N_NODES) excl[base + 3] = run;
}

__global__ void scan_mid(int* __restrict__ bsum, int nb) {
    if (threadIdx.x == 0 && blockIdx.x == 0) {
        int run = 0;
        for (int i = 0; i < nb; ++i) { int x = bsum[i]; bsum[i] = run; run += x; }
    }
}

__global__ __launch_bounds__(256) void scan_add(int* __restrict__ ptrv,
                                                const int* __restrict__ bsum,
                                                int* __restrict__ cnt,
                                                float* __restrict__ dinv) {
    int i = blockIdx.x * 256 + threadIdx.x;
    if (i < N_NODES) {
        int c = cnt[i];
        dinv[i] = rsqrtf((float)(c + 1));
        ptrv[i] += bsum[i >> 10];
        cnt[i] = 0;
    }
    if (i == 0) ptrv[N_NODES] = NE;
}

// scatter src index only (4 B/edge; weight recomputed in propagate)
__global__ __launch_bounds__(256) void fill_csr(const int* __restrict__ rowp,
                                                const int* __restrict__ colp,
                                                const int* __restrict__ ptrv,
                                                int* __restrict__ cnt,
                                                int* __restrict__ srcv) {
    int e = blockIdx.x * 256 + threadIdx.x;
    if (e < NE) {
        int c = colp[e];
        int pos = ptrv[c] + atomicAdd(&cnt[c], 1);
        srcv[pos] = rowp[e];
    }
}

// ---------------------------------------------------------------------------
// casts
// ---------------------------------------------------------------------------
// x -> slice 0 of Tbig [NPAD][640] fp16 (row stride 320 uints)
__global__ __launch_bounds__(256) void xcast(const float* __restrict__ x,
                                             unsigned* __restrict__ Tbig) {
    int idx = blockIdx.x * 256 + threadIdx.x;
    if (idx >= NPAD * 64) return;
    int m = idx >> 6, u = idx & 63;
    int e = (m << 7) + u * 2;
    float a = (m < N_NODES) ? x[e]     : 0.f;
    float b = (m < N_NODES) ? x[e + 1] : 0.f;
    Tbig[m * 320 + u] = pk2(a, b);
}

// Wt[g][i][k8][n][k7] = (half) W_g[i][k8*8+k7][n]   (chunk-transposed for LDS)
__global__ __launch_bounds__(256) void wcast(const float* __restrict__ Wo,
                                             const float* __restrict__ Wa,
                                             unsigned short* __restrict__ Wt) {
    int idx = blockIdx.x * 256 + threadIdx.x;
    if (idx >= 2 * 5 * DIM * DIM) return;
    int g   = idx / (5 * DIM * DIM);
    int rem = idx % (5 * DIM * DIM);
    int i   = rem / (DIM * DIM);
    int r2  = rem % (DIM * DIM);
    int k8  = r2 >> 10;
    int n   = (r2 >> 3) & 127;
    int k7  = r2 & 7;
    int k   = k8 * 8 + k7;
    const float* W = g ? Wa : Wo;
    Wt[idx] = f2hbits(W[(i * DIM + k) * DIM + n]);
}

// ---------------------------------------------------------------------------
// Propagation: one wave per node. All per-edge metadata (src index, dinv)
// goes through the SCALAR pipe (wave-uniform addresses -> s_load); the
// vector pipe carries only the 256 B row gathers, 16-deep.
// ---------------------------------------------------------------------------
__global__ __launch_bounds__(256) void propagate(const unsigned* __restrict__ Tin,
                                                 unsigned* __restrict__ Tout,
                                                 const int* __restrict__ ptrv,
                                                 const int* __restrict__ srcv,
                                                 const float* __restrict__ dinv) {
    int gid  = blockIdx.x * 256 + threadIdx.x;
    int lane = threadIdx.x & 63;
    int v    = __builtin_amdgcn_readfirstlane(gid >> 6);
    if (v >= N_NODES) return;
    float dv = dinv[v];
    float2 self = up2(Tin[v * 320 + lane]);
    float ax = dv * dv * self.x;
    float ay = dv * dv * self.y;
    int beg = ptrv[v], end = ptrv[v + 1];
    int k = beg;
    // main: 16 gathers in flight, scalar metadata
    for (; k + 16 <= end; k += 16) {
        int u[16];
#pragma unroll
        for (int j = 0; j < 16; ++j) u[j] = srcv[k + j];
        float2 tt[16];
#pragma unroll
        for (int j = 0; j < 16; ++j) tt[j] = up2(Tin[u[j] * 320 + lane]);
        float w[16];
#pragma unroll
        for (int j = 0; j < 16; ++j) w[j] = dinv[u[j]] * dv;
#pragma unroll
        for (int j = 0; j < 16; ++j) { ax += w[j] * tt[j].x; ay += w[j] * tt[j].y; }
    }
    for (; k + 4 <= end; k += 4) {
        int u[4];
#pragma unroll
        for (int j = 0; j < 4; ++j) u[j] = srcv[k + j];
        float2 tt[4];
#pragma unroll
        for (int j = 0; j < 4; ++j) tt[j] = up2(Tin[u[j] * 320 + lane]);
        float w[4];
#pragma unroll
        for (int j = 0; j < 4; ++j) w[j] = dinv[u[j]] * dv;
#pragma unroll
        for (int j = 0; j < 4; ++j) { ax += w[j] * tt[j].x; ay += w[j] * tt[j].y; }
    }
    for (; k < end; ++k) {
        int u = srcv[k];
        float w = dinv[u] * dv;
        float2 t = up2(Tin[u * 320 + lane]);
        ax += w * t.x; ay += w * t.y;
    }
    Tout[v * 320 + lane] = pk2(ax, ay);
}

// ---------------------------------------------------------------------------
// C[M x 128] = A[M x 640] @ W[640 x 128] via fp16 MFMA.
// Block: 256 thr / 4 waves, BM = 128 (32 rows per wave), all 128 cols.
// Per order i: B_i (32 KB, chunk-transposed [k8][n][8]) staged to LDS via
// global_load_lds (per-lane global addr + wave-uniform LDS base);
// A-frags prefetched into regs before the staging barrier.
// ---------------------------------------------------------------------------
__global__ __launch_bounds__(256, 3) void gemmK(const unsigned short* __restrict__ A,
                                                const unsigned short* __restrict__ Wt,
                                                float* __restrict__ C) {
    __shared__ unsigned short Bl[DIM * DIM];   // 32 KB
    int t = threadIdx.x;
    int lane = t & 63, wv = t >> 6;
    int m0 = blockIdx.x * 128 + wv * 32;
    int l15 = lane & 15, q = lane >> 4;
    f4 acc[2][8];
#pragma unroll
    for (int mt = 0; mt < 2; ++mt)
#pragma unroll
        for (int nt = 0; nt < 8; ++nt) acc[mt][nt] = (f4)(0.f);

#pragma unroll
    for (int i = 0; i < 5; ++i) {
        const unsigned short* WtI = Wt + (size_t)i * DIM * DIM;
        // A-frag prefetch (latency drains together with the async staging)
        h8 af[2][4];
#pragma unroll
        for (int mt = 0; mt < 2; ++mt)
#pragma unroll
            for (int kc = 0; kc < 4; ++kc)
                af[mt][kc] = *(const h8*)(A + (size_t)(m0 + mt * 16 + l15) * KTOT
                                            + i * DIM + (kc * 4 + q) * 8);
        // stage B_i: 32 chunks x 1 KB; lane supplies its own 16 B slice,
        // HW scatters to (uniform LDS base) + lane*16
#pragma unroll
        for (int c = 0; c < 8; ++c) {
            int ci = c * 4 + wv;
            async_cp16(WtI + ci * 512 + lane * 8, &Bl[ci * 512]);
        }
        __syncthreads();
#pragma unroll
        for (int kc = 0; kc < 4; ++kc) {
            int c = kc * 4 + q;
#pragma unroll
            for (int nt = 0; nt < 8; ++nt) {
                h8 bf = *(const h8*)&Bl[(size_t)(c * 128 + nt * 16 + l15) * 8];
                acc[0][nt] = __builtin_amdgcn_mfma_f32_16x16x32_f16(af[0][kc], bf, acc[0][nt], 0, 0, 0);
                acc[1][nt] = __builtin_amdgcn_mfma_f32_16x16x32_f16(af[1][kc], bf, acc[1][nt], 0, 0, 0);
            }
        }
        __syncthreads();
    }
#pragma unroll
    for (int mt = 0; mt < 2; ++mt)
#pragma unroll
        for (int nt = 0; nt < 8; ++nt)
#pragma unroll
            for (int r = 0; r < 4; ++r)
                C[(size_t)(m0 + mt * 16 + q * 4 + r) * DIM + nt * 16 + l15] = acc[mt][nt][r];
}

// ---------------------------------------------------------------------------
// out = (w0*relu(accO + sum bO) + w1*relu(accA + sum bA)) @ clfW + clfB
// ---------------------------------------------------------------------------
__global__ __launch_bounds__(256) void fuse_clf(const float* __restrict__ accO,
                                                const float* __restrict__ accA,
                                                const float* __restrict__ bO,
                                                const float* __restrict__ bA,
                                                const float* __restrict__ fw,
                                                const float* __restrict__ clfW,
                                                const float* __restrict__ clfB,
                                                float* __restrict__ out) {
    __shared__ float Wl[DIM * ODIM];
    __shared__ float Hl[32 * DIM];
    __shared__ float bs[2][DIM];
    int t = threadIdx.x;
    float f0 = fw[0], f1 = fw[1];
    float m = fmaxf(f0, f1);
    float e0 = expf(f0 - m), e1 = expf(f1 - m);
    float sw0 = e0 / (e0 + e1), sw1 = e1 / (e0 + e1);
    if (t < 128) {
        float s = 0.f;
        for (int i = 0; i <= NORDER; ++i) s += bO[i * DIM + t];
        bs[0][t] = s;
    } else {
        int j = t - 128;
        float s = 0.f;
        for (int i = 0; i <= NORDER; ++i) s += bA[i * DIM + j];
        bs[1][j] = s;
    }
    for (int i = 0; i < 8; ++i) {
        int idx = (i * 256 + t) * 4;
        *(float4*)&Wl[idx] = *(const float4*)&clfW[idx];
    }
    __syncthreads();
    int rowBase = blockIdx.x * 32;
    for (int i = 0; i < 4; ++i) {
        int idx = (i * 256 + t) * 4;
        int kcol = idx & 127;
        float4 a = *(const float4*)&accO[rowBase * DIM + idx];
        float4 b = *(const float4*)&accA[rowBase * DIM + idx];
        float4 h;
        h.x = sw0 * fmaxf(a.x + bs[0][kcol + 0], 0.f) + sw1 * fmaxf(b.x + bs[1][kcol + 0], 0.f);
        h.y = sw0 * fmaxf(a.y + bs[0][kcol + 1], 0.f) + sw1 * fmaxf(b.y + bs[1][kcol + 1], 0.f);
        h.z = sw0 * fmaxf(a.z + bs[0][kcol + 2], 0.f) + sw1 * fmaxf(b.z + bs[1][kcol + 2], 0.f);
        h.w = sw0 * fmaxf(a.w + bs[0][kcol + 3], 0.f) + sw1 * fmaxf(b.w + bs[1][kcol + 3], 0.f);
        *(float4*)&Hl[idx] = h;
    }
    __syncthreads();
    int lane = t & 63, w = t >> 6;
    int c2 = (lane & 31) * 2;
    int r0 = w * 8 + (lane >> 5) * 4;
    float acc[4][2];
    for (int j = 0; j < 4; ++j) { acc[j][0] = 0.f; acc[j][1] = 0.f; }
    for (int k0 = 0; k0 < DIM; k0 += 4) {
        float4 a0 = *(const float4*)&Hl[(r0 + 0) * DIM + k0];
        float4 a1 = *(const float4*)&Hl[(r0 + 1) * DIM + k0];
        float4 a2 = *(const float4*)&Hl[(r0 + 2) * DIM + k0];
        float4 a3 = *(const float4*)&Hl[(r0 + 3) * DIM + k0];
#define FSTEP(comp, kk)                                                      \
        {                                                                    \
            float2 wv = *(const float2*)&Wl[(k0 + kk) * ODIM + c2];          \
            acc[0][0] += a0.comp * wv.x; acc[0][1] += a0.comp * wv.y;        \
            acc[1][0] += a1.comp * wv.x; acc[1][1] += a1.comp * wv.y;        \
            acc[2][0] += a2.comp * wv.x; acc[2][1] += a2.comp * wv.y;        \
            acc[3][0] += a3.comp * wv.x; acc[3][1] += a3.comp * wv.y;        \
        }
        FSTEP(x, 0) FSTEP(y, 1) FSTEP(z, 2) FSTEP(w, 3)
#undef FSTEP
    }
    float2 cb2 = *(const float2*)&clfB[c2];
    for (int j = 0; j < 4; ++j) {
        float2 o = make_float2(acc[j][0] + cb2.x, acc[j][1] + cb2.y);
        *(float2*)&out[(rowBase + r0 + j) * ODIM + c2] = o;
    }
}

// ---------------------------------------------------------------------------
extern "C" void kernel_launch(void* const* d_in, const int* in_sizes, int n_in,
                              void* d_out, int out_size, void* d_ws, size_t ws_size,
                              hipStream_t stream) {
    const float* x   = (const float*)d_in[0];
    const int*   ei  = (const int*)d_in[1];
    const int*   gi  = (const int*)d_in[2];
    const float* w_o = (const float*)d_in[3];
    const float* b_o = (const float*)d_in[4];
    const float* w_a = (const float*)d_in[5];
    const float* b_a = (const float*)d_in[6];
    const float* fw  = (const float*)d_in[7];
    const float* cw  = (const float*)d_in[8];
    const float* cb  = (const float*)d_in[9];
    float* out = (float*)d_out;

    char* p = (char*)d_ws;
    auto alloc = [&](size_t bytes) {
        void* r = (void*)p;
        p += (bytes + 255) & ~(size_t)255;
        return r;
    };
    unsigned* Tbig = (unsigned*)alloc((size_t)NPAD * 320 * 4);        // [NPAD][640] fp16
    float* acc_o = (float*)alloc((size_t)NPAD * DIM * 4);
    float* acc_a = (float*)alloc((size_t)NPAD * DIM * 4);
    unsigned short* Wt = (unsigned short*)alloc((size_t)2 * 5 * DIM * DIM * 2);
    float* dinv  = (float*)alloc((size_t)N_NODES * 4);
    int* csr_src = (int*)alloc((size_t)NE * 4);
    int* csr_ptr = (int*)alloc((size_t)(N_NODES + 1) * 4);
    int* cnt     = (int*)alloc((size_t)N_NODES * 4);
    int* bsum    = (int*)alloc(128 * 4);

    const int gN  = (N_NODES + 255) / 256;          // 391
    const int gE  = (NE + 255) / 256;               // 6250
    const int gE4 = (NE / 4 + 255) / 256;           // 1563
    const int gS  = (N_NODES + 1023) / 1024;        // 98
    const int gP  = (N_NODES * 64 + 255) / 256;     // 25000
    const int gX  = (NPAD * 64 + 255) / 256;        // 25024
    const int gW  = (2 * 5 * DIM * DIM + 255) / 256;
    const int gM  = NPAD / 128;                     // 782
    const int gF  = N_NODES / 32;                   // 3125

    xcast<<<gX, 256, 0, stream>>>(x, Tbig);
    wcast<<<gW, 256, 0, stream>>>(w_o, w_a, Wt);

    for (int g = 0; g < 2; ++g) {
        const int* edges = g ? gi : ei;
        const int* rowp = edges;
        const int* colp = edges + NE;
        float* acc = g ? acc_a : acc_o;
        const unsigned short* Wtg = Wt + (size_t)g * 5 * DIM * DIM;

        zero_cnt<<<gN, 256, 0, stream>>>(cnt);
        count_edges<<<gE4, 256, 0, stream>>>(colp, cnt);
        scan_block<<<gS, 256, 0, stream>>>(cnt, csr_ptr, bsum);
        scan_mid<<<1, 64, 0, stream>>>(bsum, gS);
        scan_add<<<gN, 256, 0, stream>>>(csr_ptr, bsum, cnt, dinv);
        fill_csr<<<gE, 256, 0, stream>>>(rowp, colp, csr_ptr, cnt, csr_src);

        for (int i = 1; i <= NORDER; ++i)
            propagate<<<gP, 256, 0, stream>>>(Tbig + (i - 1) * 64, Tbig + i * 64,
                                              csr_ptr, csr_src, dinv);

        gemmK<<<gM, 256, 0, stream>>>((const unsigned short*)Tbig, Wtg, acc);
    }
    fuse_clf<<<gF, 256, 0, stream>>>(acc_o, acc_a, b_o, b_a, fw, cw, cb, out);
}

// Round 6
// 1022.496 us; speedup vs baseline: 1.9460x; 1.0343x over previous
//
#include <hip/hip_runtime.h>

#define N_NODES 100000
#define NPAD    100096      // multiple of 128 for GEMM tiles
#define NE      1600000
#define DIM     128
#define ODIM    64
#define NORDER  4
#define KTOT    640         // 5 * 128, T stored as one M x 640 matrix
#define NB      391         // buckets of 256 nodes (node >> 8)

typedef _Float16 h8 __attribute__((ext_vector_type(8)));
typedef float f4 __attribute__((ext_vector_type(4)));

__device__ __forceinline__ float2 up2(unsigned p) {
    union { unsigned u; _Float16 h[2]; } c; c.u = p;
    return make_float2((float)c.h[0], (float)c.h[1]);
}
__device__ __forceinline__ unsigned pk2(float x, float y) {
    union { unsigned u; _Float16 h[2]; } c;
    c.h[0] = (_Float16)x; c.h[1] = (_Float16)y;
    return c.u;
}
__device__ __forceinline__ unsigned short f2hbits(float x) {
    union { _Float16 h; unsigned short s; } c;
    c.h = (_Float16)x;
    return c.s;
}
__device__ __forceinline__ void async_cp16(const void* g, void* l) {
    __builtin_amdgcn_global_load_lds((const __attribute__((address_space(1))) void*)g,
                                     (__attribute__((address_space(3))) void*)l, 16, 0, 0);
}

// ---------------------------------------------------------------------------
// CSR build — binned to kill partial-line writeback amplification
// ---------------------------------------------------------------------------
__global__ __launch_bounds__(256) void zero_cnt(int* __restrict__ cnt,
                                                int* __restrict__ bhist) {
    int i = blockIdx.x * 256 + threadIdx.x;
    if (i < N_NODES) cnt[i] = 0;
    if (i < NB) bhist[i] = 0;
}

// degree count (global atomics, low contention) + bucket histogram (LDS)
__global__ __launch_bounds__(256) void hist_edges(const int* __restrict__ colp,
                                                  int* __restrict__ cnt,
                                                  int* __restrict__ bhist) {
    __shared__ int lh[NB];
    int t = threadIdx.x;
    for (int i = t; i < NB; i += 256) lh[i] = 0;
    __syncthreads();
    int base = blockIdx.x * 4096 + t;
#pragma unroll
    for (int j = 0; j < 16; ++j) {
        int e = base + j * 256;
        if (e < NE) {
            int c = colp[e];
            atomicAdd(&cnt[c], 1);
            atomicAdd(&lh[c >> 8], 1);
        }
    }
    __syncthreads();
    for (int i = t; i < NB; i += 256) if (lh[i]) atomicAdd(&bhist[i], lh[i]);
}

__global__ __launch_bounds__(256) void scan_block(const int* __restrict__ cnt,
                                                  int* __restrict__ excl,
                                                  int* __restrict__ bsum) {
    __shared__ int lds[256];
    int t = threadIdx.x, b = blockIdx.x;
    int base = b * 1024 + t * 4;
    int v0 = (base + 0 < N_NODES) ? cnt[base + 0] : 0;
    int v1 = (base + 1 < N_NODES) ? cnt[base + 1] : 0;
    int v2 = (base + 2 < N_NODES) ? cnt[base + 2] : 0;
    int v3 = (base + 3 < N_NODES) ? cnt[base + 3] : 0;
    int tot = v0 + v1 + v2 + v3;
    lds[t] = tot;
    __syncthreads();
    for (int off = 1; off < 256; off <<= 1) {
        int x = (t >= off) ? lds[t - off] : 0;
        __syncthreads();
        lds[t] += x;
        __syncthreads();
    }
    int run = lds[t] - tot;
    if (t == 255) bsum[b] = lds[255];
    if (base + 0 < N_NODES) excl[base + 0] = run; run += v0;
    if (base + 1 < N_NODES) excl[base + 1] = run; run += v1;
    if (base + 2 < N_NODES) excl[base + 2] = run; run += v2;
    if (base + 3 < N_NODES) excl[base + 3] = run;
}

__global__ void scan_mid(int* __restrict__ bsum, int nb) {
    if (threadIdx.x == 0 && blockIdx.x == 0) {
        int run = 0;
        for (int i = 0; i < nb; ++i) { int x = bsum[i]; bsum[i] = run; run += x; }
    }
}

__global__ __launch_bounds__(256) void scan_add(int* __restrict__ ptrv,
                                                const int* __restrict__ bsum,
                                                const int* __restrict__ cnt,
                                                float* __restrict__ dinv) {
    int i = blockIdx.x * 256 + threadIdx.x;
    if (i < N_NODES) {
        dinv[i] = rsqrtf((float)(cnt[i] + 1));
        ptrv[i] += bsum[i >> 10];
    }
    if (i == 0) ptrv[N_NODES] = NE;
}

// bucket offsets + cursors (NB=391, trivial serial scan)
__global__ void bscan(const int* __restrict__ bhist,
                      int* __restrict__ boff,
                      int* __restrict__ bcursor) {
    if (threadIdx.x == 0 && blockIdx.x == 0) {
        int run = 0;
        for (int i = 0; i < NB; ++i) {
            boff[i] = run; bcursor[i] = run; run += bhist[i];
        }
        boff[NB] = run;
    }
}

// partition edges into buckets; per-block chunks -> write-local lines
__global__ __launch_bounds__(256) void part_edges(const int* __restrict__ rowp,
                                                  const int* __restrict__ colp,
                                                  int* __restrict__ bcursor,
                                                  int2* __restrict__ pairs) {
    __shared__ int lh[NB];
    __shared__ int lpos[NB];
    int t = threadIdx.x;
    for (int i = t; i < NB; i += 256) lh[i] = 0;
    __syncthreads();
    int base = blockIdx.x * 4096 + t;
    int rank[16];
    short bk[16];
#pragma unroll
    for (int j = 0; j < 16; ++j) {
        int e = base + j * 256;
        rank[j] = -1;
        if (e < NE) {
            int b = colp[e] >> 8;
            bk[j] = (short)b;
            rank[j] = atomicAdd(&lh[b], 1);
        }
    }
    __syncthreads();
    for (int i = t; i < NB; i += 256) {
        int n = lh[i];
        lpos[i] = n ? atomicAdd(&bcursor[i], n) : 0;
    }
    __syncthreads();
#pragma unroll
    for (int j = 0; j < 16; ++j) {
        int e = base + j * 256;
        if (e < NE) {
            int b = bk[j];
            pairs[lpos[b] + rank[j]] = make_int2(rowp[e], colp[e]);
        }
    }
}

// fine scatter: one block per bucket, per-node counters in LDS,
// csr_src writes land in a contiguous ~16 KB window owned by this block
__global__ __launch_bounds__(256) void fine_csr(const int2* __restrict__ pairs,
                                                const int* __restrict__ boff,
                                                const int* __restrict__ ptrv,
                                                int* __restrict__ srcv) {
    __shared__ int lcnt[256];
    int t = threadIdx.x, b = blockIdx.x;
    lcnt[t] = 0;
    __syncthreads();
    int s = boff[b], e = boff[b + 1];
    int base = b << 8;
    for (int i = s + t; i < e; i += 256) {
        int2 pr = pairs[i];
        int pos = ptrv[pr.y] + atomicAdd(&lcnt[pr.y - base], 1);
        srcv[pos] = pr.x;
    }
}

// ---------------------------------------------------------------------------
// casts
// ---------------------------------------------------------------------------
// x -> slice 0 of Tbig [NPAD][640] fp16 (row stride 320 uints)
__global__ __launch_bounds__(256) void xcast(const float* __restrict__ x,
                                             unsigned* __restrict__ Tbig) {
    int idx = blockIdx.x * 256 + threadIdx.x;
    if (idx >= NPAD * 64) return;
    int m = idx >> 6, u = idx & 63;
    int e = (m << 7) + u * 2;
    float a = (m < N_NODES) ? x[e]     : 0.f;
    float b = (m < N_NODES) ? x[e + 1] : 0.f;
    Tbig[m * 320 + u] = pk2(a, b);
}

// Wt[g][i][k8][n][k7] = (half) W_g[i][k8*8+k7][n]   (chunk-transposed for LDS)
__global__ __launch_bounds__(256) void wcast(const float* __restrict__ Wo,
                                             const float* __restrict__ Wa,
                                             unsigned short* __restrict__ Wt) {
    int idx = blockIdx.x * 256 + threadIdx.x;
    if (idx >= 2 * 5 * DIM * DIM) return;
    int g   = idx / (5 * DIM * DIM);
    int rem = idx % (5 * DIM * DIM);
    int i   = rem / (DIM * DIM);
    int r2  = rem % (DIM * DIM);
    int k8  = r2 >> 10;
    int n   = (r2 >> 3) & 127;
    int k7  = r2 & 7;
    int k   = k8 * 8 + k7;
    const float* W = g ? Wa : Wo;
    Wt[idx] = f2hbits(W[(i * DIM + k) * DIM + n]);
}

// ---------------------------------------------------------------------------
// Propagation: one wave per node; scalar pipe for metadata, vector pipe
// carries only the 256 B row gathers, 16-deep.
// ---------------------------------------------------------------------------
__global__ __launch_bounds__(256) void propagate(const unsigned* __restrict__ Tin,
                                                 unsigned* __restrict__ Tout,
                                                 const int* __restrict__ ptrv,
                                                 const int* __restrict__ srcv,
                                                 const float* __restrict__ dinv) {
    int gid  = blockIdx.x * 256 + threadIdx.x;
    int lane = threadIdx.x & 63;
    int v    = __builtin_amdgcn_readfirstlane(gid >> 6);
    if (v >= N_NODES) return;
    float dv = dinv[v];
    float2 self = up2(Tin[v * 320 + lane]);
    float ax = dv * dv * self.x;
    float ay = dv * dv * self.y;
    int beg = ptrv[v], end = ptrv[v + 1];
    int k = beg;
    for (; k + 16 <= end; k += 16) {
        int u[16];
#pragma unroll
        for (int j = 0; j < 16; ++j) u[j] = srcv[k + j];
        float2 tt[16];
#pragma unroll
        for (int j = 0; j < 16; ++j) tt[j] = up2(Tin[u[j] * 320 + lane]);
        float w[16];
#pragma unroll
        for (int j = 0; j < 16; ++j) w[j] = dinv[u[j]] * dv;
#pragma unroll
        for (int j = 0; j < 16; ++j) { ax += w[j] * tt[j].x; ay += w[j] * tt[j].y; }
    }
    for (; k + 4 <= end; k += 4) {
        int u[4];
#pragma unroll
        for (int j = 0; j < 4; ++j) u[j] = srcv[k + j];
        float2 tt[4];
#pragma unroll
        for (int j = 0; j < 4; ++j) tt[j] = up2(Tin[u[j] * 320 + lane]);
        float w[4];
#pragma unroll
        for (int j = 0; j < 4; ++j) w[j] = dinv[u[j]] * dv;
#pragma unroll
        for (int j = 0; j < 4; ++j) { ax += w[j] * tt[j].x; ay += w[j] * tt[j].y; }
    }
    for (; k < end; ++k) {
        int u = srcv[k];
        float w = dinv[u] * dv;
        float2 t = up2(Tin[u * 320 + lane]);
        ax += w * t.x; ay += w * t.y;
    }
    Tout[v * 320 + lane] = pk2(ax, ay);
}

// ---------------------------------------------------------------------------
// C[M x 128] = A[M x 640] @ W[640 x 128] via fp16 MFMA.
// ---------------------------------------------------------------------------
__global__ __launch_bounds__(256, 3) void gemmK(const unsigned short* __restrict__ A,
                                                const unsigned short* __restrict__ Wt,
                                                float* __restrict__ C) {
    __shared__ unsigned short Bl[DIM * DIM];   // 32 KB
    int t = threadIdx.x;
    int lane = t & 63, wv = t >> 6;
    int m0 = blockIdx.x * 128 + wv * 32;
    int l15 = lane & 15, q = lane >> 4;
    f4 acc[2][8];
#pragma unroll
    for (int mt = 0; mt < 2; ++mt)
#pragma unroll
        for (int nt = 0; nt < 8; ++nt) acc[mt][nt] = (f4)(0.f);

#pragma unroll
    for (int i = 0; i < 5; ++i) {
        const unsigned short* WtI = Wt + (size_t)i * DIM * DIM;
        h8 af[2][4];
#pragma unroll
        for (int mt = 0; mt < 2; ++mt)
#pragma unroll
            for (int kc = 0; kc < 4; ++kc)
                af[mt][kc] = *(const h8*)(A + (size_t)(m0 + mt * 16 + l15) * KTOT
                                            + i * DIM + (kc * 4 + q) * 8);
#pragma unroll
        for (int c = 0; c < 8; ++c) {
            int ci = c * 4 + wv;
            async_cp16(WtI + ci * 512 + lane * 8, &Bl[ci * 512]);
        }
        __syncthreads();
#pragma unroll
        for (int kc = 0; kc < 4; ++kc) {
            int c = kc * 4 + q;
#pragma unroll
            for (int nt = 0; nt < 8; ++nt) {
                h8 bf = *(const h8*)&Bl[(size_t)(c * 128 + nt * 16 + l15) * 8];
                acc[0][nt] = __builtin_amdgcn_mfma_f32_16x16x32_f16(af[0][kc], bf, acc[0][nt], 0, 0, 0);
                acc[1][nt] = __builtin_amdgcn_mfma_f32_16x16x32_f16(af[1][kc], bf, acc[1][nt], 0, 0, 0);
            }
        }
        __syncthreads();
    }
#pragma unroll
    for (int mt = 0; mt < 2; ++mt)
#pragma unroll
        for (int nt = 0; nt < 8; ++nt)
#pragma unroll
            for (int r = 0; r < 4; ++r)
                C[(size_t)(m0 + mt * 16 + q * 4 + r) * DIM + nt * 16 + l15] = acc[mt][nt][r];
}

// ---------------------------------------------------------------------------
// out = (w0*relu(accO + sum bO) + w1*relu(accA + sum bA)) @ clfW + clfB
// ---------------------------------------------------------------------------
__global__ __launch_bounds__(256) void fuse_clf(const float* __restrict__ accO,
                                                const float* __restrict__ accA,
                                                const float* __restrict__ bO,
                                                const float* __restrict__ bA,
                                                const float* __restrict__ fw,
                                                const float* __restrict__ clfW,
                                                const float* __restrict__ clfB,
                                                float* __restrict__ out) {
    __shared__ float Wl[DIM * ODIM];
    __shared__ float Hl[32 * DIM];
    __shared__ float bs[2][DIM];
    int t = threadIdx.x;
    float f0 = fw[0], f1 = fw[1];
    float m = fmaxf(f0, f1);
    float e0 = expf(f0 - m), e1 = expf(f1 - m);
    float sw0 = e0 / (e0 + e1), sw1 = e1 / (e0 + e1);
    if (t < 128) {
        float s = 0.f;
        for (int i = 0; i <= NORDER; ++i) s += bO[i * DIM + t];
        bs[0][t] = s;
    } else {
        int j = t - 128;
        float s = 0.f;
        for (int i = 0; i <= NORDER; ++i) s += bA[i * DIM + j];
        bs[1][j] = s;
    }
    for (int i = 0; i < 8; ++i) {
        int idx = (i * 256 + t) * 4;
        *(float4*)&Wl[idx] = *(const float4*)&clfW[idx];
    }
    __syncthreads();
    int rowBase = blockIdx.x * 32;
    for (int i = 0; i < 4; ++i) {
        int idx = (i * 256 + t) * 4;
        int kcol = idx & 127;
        float4 a = *(const float4*)&accO[rowBase * DIM + idx];
        float4 b = *(const float4*)&accA[rowBase * DIM + idx];
        float4 h;
        h.x = sw0 * fmaxf(a.x + bs[0][kcol + 0], 0.f) + sw1 * fmaxf(b.x + bs[1][kcol + 0], 0.f);
        h.y = sw0 * fmaxf(a.y + bs[0][kcol + 1], 0.f) + sw1 * fmaxf(b.y + bs[1][kcol + 1], 0.f);
        h.z = sw0 * fmaxf(a.z + bs[0][kcol + 2], 0.f) + sw1 * fmaxf(b.z + bs[1][kcol + 2], 0.f);
        h.w = sw0 * fmaxf(a.w + bs[0][kcol + 3], 0.f) + sw1 * fmaxf(b.w + bs[1][kcol + 3], 0.f);
        *(float4*)&Hl[idx] = h;
    }
    __syncthreads();
    int lane = t & 63, w = t >> 6;
    int c2 = (lane & 31) * 2;
    int r0 = w * 8 + (lane >> 5) * 4;
    float acc[4][2];
    for (int j = 0; j < 4; ++j) { acc[j][0] = 0.f; acc[j][1] = 0.f; }
    for (int k0 = 0; k0 < DIM; k0 += 4) {
        float4 a0 = *(const float4*)&Hl[(r0 + 0) * DIM + k0];
        float4 a1 = *(const float4*)&Hl[(r0 + 1) * DIM + k0];
        float4 a2 = *(const float4*)&Hl[(r0 + 2) * DIM + k0];
        float4 a3 = *(const float4*)&Hl[(r0 + 3) * DIM + k0];
#define FSTEP(comp, kk)                                                      \
        {                                                                    \
            float2 wv = *(const float2*)&Wl[(k0 + kk) * ODIM + c2];          \
            acc[0][0] += a0.comp * wv.x; acc[0][1] += a0.comp * wv.y;        \
            acc[1][0] += a1.comp * wv.x; acc[1][1] += a1.comp * wv.y;        \
            acc[2][0] += a2.comp * wv.x; acc[2][1] += a2.comp * wv.y;        \
            acc[3][0] += a3.comp * wv.x; acc[3][1] += a3.comp * wv.y;        \
        }
        FSTEP(x, 0) FSTEP(y, 1) FSTEP(z, 2) FSTEP(w, 3)
#undef FSTEP
    }
    float2 cb2 = *(const float2*)&clfB[c2];
    for (int j = 0; j < 4; ++j) {
        float2 o = make_float2(acc[j][0] + cb2.x, acc[j][1] + cb2.y);
        *(float2*)&out[(rowBase + r0 + j) * ODIM + c2] = o;
    }
}

// ---------------------------------------------------------------------------
extern "C" void kernel_launch(void* const* d_in, const int* in_sizes, int n_in,
                              void* d_out, int out_size, void* d_ws, size_t ws_size,
                              hipStream_t stream) {
    const float* x   = (const float*)d_in[0];
    const int*   ei  = (const int*)d_in[1];
    const int*   gi  = (const int*)d_in[2];
    const float* w_o = (const float*)d_in[3];
    const float* b_o = (const float*)d_in[4];
    const float* w_a = (const float*)d_in[5];
    const float* b_a = (const float*)d_in[6];
    const float* fw  = (const float*)d_in[7];
    const float* cw  = (const float*)d_in[8];
    const float* cb  = (const float*)d_in[9];
    float* out = (float*)d_out;

    char* p = (char*)d_ws;
    auto alloc = [&](size_t bytes) {
        void* r = (void*)p;
        p += (bytes + 255) & ~(size_t)255;
        return r;
    };
    unsigned* Tbig = (unsigned*)alloc((size_t)NPAD * 320 * 4);        // [NPAD][640] fp16
    float* acc_o = (float*)alloc((size_t)NPAD * DIM * 4);
    float* acc_a = (float*)alloc((size_t)NPAD * DIM * 4);
    unsigned short* Wt = (unsigned short*)alloc((size_t)2 * 5 * DIM * DIM * 2);
    float* dinv  = (float*)alloc((size_t)N_NODES * 4);
    int2* pairs  = (int2*)alloc((size_t)NE * 8);
    int* csr_src = (int*)alloc((size_t)NE * 4);
    int* csr_ptr = (int*)alloc((size_t)(N_NODES + 1) * 4);
    int* cnt     = (int*)alloc((size_t)N_NODES * 4);
    int* bsum    = (int*)alloc(128 * 4);
    int* bhist   = (int*)alloc((size_t)NB * 4);
    int* boff    = (int*)alloc((size_t)(NB + 1) * 4);
    int* bcursor = (int*)alloc((size_t)NB * 4);

    const int gN  = (N_NODES + 255) / 256;          // 391
    const int gH  = (NE + 4095) / 4096;             // 391
    const int gS  = (N_NODES + 1023) / 1024;        // 98
    const int gP  = (N_NODES * 64 + 255) / 256;     // 25000
    const int gX  = (NPAD * 64 + 255) / 256;        // 25024
    const int gW  = (2 * 5 * DIM * DIM + 255) / 256;
    const int gM  = NPAD / 128;                     // 782
    const int gF  = N_NODES / 32;                   // 3125

    xcast<<<gX, 256, 0, stream>>>(x, Tbig);
    wcast<<<gW, 256, 0, stream>>>(w_o, w_a, Wt);

    for (int g = 0; g < 2; ++g) {
        const int* edges = g ? gi : ei;
        const int* rowp = edges;
        const int* colp = edges + NE;
        float* acc = g ? acc_a : acc_o;
        const unsigned short* Wtg = Wt + (size_t)g * 5 * DIM * DIM;

        zero_cnt<<<gN, 256, 0, stream>>>(cnt, bhist);
        hist_edges<<<gH, 256, 0, stream>>>(colp, cnt, bhist);
        scan_block<<<gS, 256, 0, stream>>>(cnt, csr_ptr, bsum);
        scan_mid<<<1, 64, 0, stream>>>(bsum, gS);
        scan_add<<<gN, 256, 0, stream>>>(csr_ptr, bsum, cnt, dinv);
        bscan<<<1, 64, 0, stream>>>(bhist, boff, bcursor);
        part_edges<<<gH, 256, 0, stream>>>(rowp, colp, bcursor, pairs);
        fine_csr<<<NB, 256, 0, stream>>>(pairs, boff, csr_ptr, csr_src);

        for (int i = 1; i <= NORDER; ++i)
            propagate<<<gP, 256, 0, stream>>>(Tbig + (i - 1) * 64, Tbig + i * 64,
                                              csr_ptr, csr_src, dinv);

        gemmK<<<gM, 256, 0, stream>>>((const unsigned short*)Tbig, Wtg, acc);
    }
    fuse_clf<<<gF, 256, 0, stream>>>(acc_o, acc_a, b_o, b_a, fw, cw, cb, out);
}

// Round 7
// 937.322 us; speedup vs baseline: 2.1228x; 1.0909x over previous
//
#include <hip/hip_runtime.h>

#define N_NODES 100000
#define NPAD    100096      // multiple of 128 for GEMM tiles
#define NE      1600000
#define DIM     128
#define ODIM    64
#define NORDER  4
#define KTOT    640         // 5 * 128, T stored as one M x 640 matrix
#define NB      391         // buckets of 256 nodes (node >> 8)

typedef _Float16 h8 __attribute__((ext_vector_type(8)));
typedef float f4 __attribute__((ext_vector_type(4)));

__device__ __forceinline__ float2 up2(unsigned p) {
    union { unsigned u; _Float16 h[2]; } c; c.u = p;
    return make_float2((float)c.h[0], (float)c.h[1]);
}
__device__ __forceinline__ unsigned pk2(float x, float y) {
    union { unsigned u; _Float16 h[2]; } c;
    c.h[0] = (_Float16)x; c.h[1] = (_Float16)y;
    return c.u;
}
__device__ __forceinline__ unsigned short f2hbits(float x) {
    union { _Float16 h; unsigned short s; } c;
    c.h = (_Float16)x;
    return c.s;
}
__device__ __forceinline__ void async_cp16(const void* g, void* l) {
    __builtin_amdgcn_global_load_lds((const __attribute__((address_space(1))) void*)g,
                                     (__attribute__((address_space(3))) void*)l, 16, 0, 0);
}

// ---------------------------------------------------------------------------
// CSR build — binned; NO per-node global atomics anywhere.
// ---------------------------------------------------------------------------
__global__ __launch_bounds__(256) void zero_b(int* __restrict__ bhist) {
    int i = blockIdx.x * 256 + threadIdx.x;
    if (i < NB) bhist[i] = 0;
}

// bucket histogram only (LDS-resident, flush once per block)
__global__ __launch_bounds__(256) void hist_edges(const int* __restrict__ colp,
                                                  int* __restrict__ bhist) {
    __shared__ int lh[NB];
    int t = threadIdx.x;
    for (int i = t; i < NB; i += 256) lh[i] = 0;
    __syncthreads();
    int base = blockIdx.x * 2048 + t;
#pragma unroll
    for (int j = 0; j < 8; ++j) {
        int e = base + j * 256;
        if (e < NE) atomicAdd(&lh[colp[e] >> 8], 1);
    }
    __syncthreads();
    for (int i = t; i < NB; i += 256) if (lh[i]) atomicAdd(&bhist[i], lh[i]);
}

// bucket offsets + cursors (NB=391, trivial serial scan)
__global__ void bscan(const int* __restrict__ bhist,
                      int* __restrict__ boff,
                      int* __restrict__ bcursor) {
    if (threadIdx.x == 0 && blockIdx.x == 0) {
        int run = 0;
        for (int i = 0; i < NB; ++i) {
            boff[i] = run; bcursor[i] = run; run += bhist[i];
        }
        boff[NB] = run;
    }
}

// partition edges into buckets; per-block chunks -> write-local lines
__global__ __launch_bounds__(256) void part_edges(const int* __restrict__ rowp,
                                                  const int* __restrict__ colp,
                                                  int* __restrict__ bcursor,
                                                  int2* __restrict__ pairs) {
    __shared__ int lh[NB];
    __shared__ int lpos[NB];
    int t = threadIdx.x;
    for (int i = t; i < NB; i += 256) lh[i] = 0;
    __syncthreads();
    int base = blockIdx.x * 4096 + t;
    int rank[16];
    short bk[16];
#pragma unroll
    for (int j = 0; j < 16; ++j) {
        int e = base + j * 256;
        rank[j] = -1;
        if (e < NE) {
            int b = colp[e] >> 8;
            bk[j] = (short)b;
            rank[j] = atomicAdd(&lh[b], 1);
        }
    }
    __syncthreads();
    for (int i = t; i < NB; i += 256) {
        int n = lh[i];
        lpos[i] = n ? atomicAdd(&bcursor[i], n) : 0;
    }
    __syncthreads();
#pragma unroll
    for (int j = 0; j < 16; ++j) {
        int e = base + j * 256;
        if (e < NE) {
            int b = bk[j];
            pairs[lpos[b] + rank[j]] = make_int2(rowp[e], colp[e]);
        }
    }
}

// per-node degree from binned pairs: LDS counters, ONE coalesced cnt write
__global__ __launch_bounds__(256) void count_fine(const int2* __restrict__ pairs,
                                                  const int* __restrict__ boff,
                                                  int* __restrict__ cnt) {
    __shared__ int lcnt[256];
    int t = threadIdx.x, b = blockIdx.x;
    lcnt[t] = 0;
    __syncthreads();
    int s = boff[b], e = boff[b + 1];
    int base = b << 8;
    for (int i = s + t; i < e; i += 256)
        atomicAdd(&lcnt[pairs[i].y - base], 1);
    __syncthreads();
    int node = base + t;
    if (node < N_NODES) cnt[node] = lcnt[t];
}

__global__ __launch_bounds__(256) void scan_block(const int* __restrict__ cnt,
                                                  int* __restrict__ excl,
                                                  int* __restrict__ bsum) {
    __shared__ int lds[256];
    int t = threadIdx.x, b = blockIdx.x;
    int base = b * 1024 + t * 4;
    int v0 = (base + 0 < N_NODES) ? cnt[base + 0] : 0;
    int v1 = (base + 1 < N_NODES) ? cnt[base + 1] : 0;
    int v2 = (base + 2 < N_NODES) ? cnt[base + 2] : 0;
    int v3 = (base + 3 < N_NODES) ? cnt[base + 3] : 0;
    int tot = v0 + v1 + v2 + v3;
    lds[t] = tot;
    __syncthreads();
    for (int off = 1; off < 256; off <<= 1) {
        int x = (t >= off) ? lds[t - off] : 0;
        __syncthreads();
        lds[t] += x;
        __syncthreads();
    }
    int run = lds[t] - tot;
    if (t == 255) bsum[b] = lds[255];
    if (base + 0 < N_NODES) excl[base + 0] = run; run += v0;
    if (base + 1 < N_NODES) excl[base + 1] = run; run += v1;
    if (base + 2 < N_NODES) excl[base + 2] = run; run += v2;
    if (base + 3 < N_NODES) excl[base + 3] = run;
}

__global__ void scan_mid(int* __restrict__ bsum, int nb) {
    if (threadIdx.x == 0 && blockIdx.x == 0) {
        int run = 0;
        for (int i = 0; i < nb; ++i) { int x = bsum[i]; bsum[i] = run; run += x; }
    }
}

__global__ __launch_bounds__(256) void scan_add(int* __restrict__ ptrv,
                                                const int* __restrict__ bsum,
                                                const int* __restrict__ cnt,
                                                float* __restrict__ dinv) {
    int i = blockIdx.x * 256 + threadIdx.x;
    if (i < N_NODES) {
        dinv[i] = rsqrtf((float)(cnt[i] + 1));
        ptrv[i] += bsum[i >> 10];
    }
    if (i == 0) ptrv[N_NODES] = NE;
}

// fine scatter: one block per bucket, per-node counters in LDS,
// csr_src writes land in a contiguous ~16 KB window owned by this block
__global__ __launch_bounds__(256) void fine_csr(const int2* __restrict__ pairs,
                                                const int* __restrict__ boff,
                                                const int* __restrict__ ptrv,
                                                int* __restrict__ srcv) {
    __shared__ int lcnt[256];
    int t = threadIdx.x, b = blockIdx.x;
    lcnt[t] = 0;
    __syncthreads();
    int s = boff[b], e = boff[b + 1];
    int base = b << 8;
    for (int i = s + t; i < e; i += 256) {
        int2 pr = pairs[i];
        int pos = ptrv[pr.y] + atomicAdd(&lcnt[pr.y - base], 1);
        srcv[pos] = pr.x;
    }
}

// ---------------------------------------------------------------------------
// casts
// ---------------------------------------------------------------------------
// x -> slice 0 of Tbig [NPAD][640] fp16 (row stride 320 uints)
__global__ __launch_bounds__(256) void xcast(const float* __restrict__ x,
                                             unsigned* __restrict__ Tbig) {
    int idx = blockIdx.x * 256 + threadIdx.x;
    if (idx >= NPAD * 64) return;
    int m = idx >> 6, u = idx & 63;
    int e = (m << 7) + u * 2;
    float a = (m < N_NODES) ? x[e]     : 0.f;
    float b = (m < N_NODES) ? x[e + 1] : 0.f;
    Tbig[m * 320 + u] = pk2(a, b);
}

// Wt[g][i][k8][n][k7] = (half) W_g[i][k8*8+k7][n]   (chunk-transposed for LDS)
__global__ __launch_bounds__(256) void wcast(const float* __restrict__ Wo,
                                             const float* __restrict__ Wa,
                                             unsigned short* __restrict__ Wt) {
    int idx = blockIdx.x * 256 + threadIdx.x;
    if (idx >= 2 * 5 * DIM * DIM) return;
    int g   = idx / (5 * DIM * DIM);
    int rem = idx % (5 * DIM * DIM);
    int i   = rem / (DIM * DIM);
    int r2  = rem % (DIM * DIM);
    int k8  = r2 >> 10;
    int n   = (r2 >> 3) & 127;
    int k7  = r2 & 7;
    int k   = k8 * 8 + k7;
    const float* W = g ? Wa : Wo;
    Wt[idx] = f2hbits(W[(i * DIM + k) * DIM + n]);
}

// ---------------------------------------------------------------------------
// Propagation: one wave per node; scalar pipe for metadata, vector pipe
// carries only the 256 B row gathers, 16-deep.
// ---------------------------------------------------------------------------
__global__ __launch_bounds__(256) void propagate(const unsigned* __restrict__ Tin,
                                                 unsigned* __restrict__ Tout,
                                                 const int* __restrict__ ptrv,
                                                 const int* __restrict__ srcv,
                                                 const float* __restrict__ dinv) {
    int gid  = blockIdx.x * 256 + threadIdx.x;
    int lane = threadIdx.x & 63;
    int v    = __builtin_amdgcn_readfirstlane(gid >> 6);
    if (v >= N_NODES) return;
    float dv = dinv[v];
    float2 self = up2(Tin[v * 320 + lane]);
    float ax = dv * dv * self.x;
    float ay = dv * dv * self.y;
    int beg = ptrv[v], end = ptrv[v + 1];
    int k = beg;
    for (; k + 16 <= end; k += 16) {
        int u[16];
#pragma unroll
        for (int j = 0; j < 16; ++j) u[j] = srcv[k + j];
        float2 tt[16];
#pragma unroll
        for (int j = 0; j < 16; ++j) tt[j] = up2(Tin[u[j] * 320 + lane]);
        float w[16];
#pragma unroll
        for (int j = 0; j < 16; ++j) w[j] = dinv[u[j]] * dv;
#pragma unroll
        for (int j = 0; j < 16; ++j) { ax += w[j] * tt[j].x; ay += w[j] * tt[j].y; }
    }
    for (; k + 4 <= end; k += 4) {
        int u[4];
#pragma unroll
        for (int j = 0; j < 4; ++j) u[j] = srcv[k + j];
        float2 tt[4];
#pragma unroll
        for (int j = 0; j < 4; ++j) tt[j] = up2(Tin[u[j] * 320 + lane]);
        float w[4];
#pragma unroll
        for (int j = 0; j < 4; ++j) w[j] = dinv[u[j]] * dv;
#pragma unroll
        for (int j = 0; j < 4; ++j) { ax += w[j] * tt[j].x; ay += w[j] * tt[j].y; }
    }
    for (; k < end; ++k) {
        int u = srcv[k];
        float w = dinv[u] * dv;
        float2 t = up2(Tin[u * 320 + lane]);
        ax += w * t.x; ay += w * t.y;
    }
    Tout[v * 320 + lane] = pk2(ax, ay);
}

// ---------------------------------------------------------------------------
// C[M x 128] = A[M x 640] @ W[640 x 128] via fp16 MFMA.
// ---------------------------------------------------------------------------
__global__ __launch_bounds__(256, 3) void gemmK(const unsigned short* __restrict__ A,
                                                const unsigned short* __restrict__ Wt,
                                                float* __restrict__ C) {
    __shared__ unsigned short Bl[DIM * DIM];   // 32 KB
    int t = threadIdx.x;
    int lane = t & 63, wv = t >> 6;
    int m0 = blockIdx.x * 128 + wv * 32;
    int l15 = lane & 15, q = lane >> 4;
    f4 acc[2][8];
#pragma unroll
    for (int mt = 0; mt < 2; ++mt)
#pragma unroll
        for (int nt = 0; nt < 8; ++nt) acc[mt][nt] = (f4)(0.f);

#pragma unroll
    for (int i = 0; i < 5; ++i) {
        const unsigned short* WtI = Wt + (size_t)i * DIM * DIM;
        h8 af[2][4];
#pragma unroll
        for (int mt = 0; mt < 2; ++mt)
#pragma unroll
            for (int kc = 0; kc < 4; ++kc)
                af[mt][kc] = *(const h8*)(A + (size_t)(m0 + mt * 16 + l15) * KTOT
                                            + i * DIM + (kc * 4 + q) * 8);
#pragma unroll
        for (int c = 0; c < 8; ++c) {
            int ci = c * 4 + wv;
            async_cp16(WtI + ci * 512 + lane * 8, &Bl[ci * 512]);
        }
        __syncthreads();
#pragma unroll
        for (int kc = 0; kc < 4; ++kc) {
            int c = kc * 4 + q;
#pragma unroll
            for (int nt = 0; nt < 8; ++nt) {
                h8 bf = *(const h8*)&Bl[(size_t)(c * 128 + nt * 16 + l15) * 8];
                acc[0][nt] = __builtin_amdgcn_mfma_f32_16x16x32_f16(af[0][kc], bf, acc[0][nt], 0, 0, 0);
                acc[1][nt] = __builtin_amdgcn_mfma_f32_16x16x32_f16(af[1][kc], bf, acc[1][nt], 0, 0, 0);
            }
        }
        __syncthreads();
    }
#pragma unroll
    for (int mt = 0; mt < 2; ++mt)
#pragma unroll
        for (int nt = 0; nt < 8; ++nt)
#pragma unroll
            for (int r = 0; r < 4; ++r)
                C[(size_t)(m0 + mt * 16 + q * 4 + r) * DIM + nt * 16 + l15] = acc[mt][nt][r];
}

// ---------------------------------------------------------------------------
// out = (w0*relu(accO + sum bO) + w1*relu(accA + sum bA)) @ clfW + clfB
// ---------------------------------------------------------------------------
__global__ __launch_bounds__(256) void fuse_clf(const float* __restrict__ accO,
                                                const float* __restrict__ accA,
                                                const float* __restrict__ bO,
                                                const float* __restrict__ bA,
                                                const float* __restrict__ fw,
                                                const float* __restrict__ clfW,
                                                const float* __restrict__ clfB,
                                                float* __restrict__ out) {
    __shared__ float Wl[DIM * ODIM];
    __shared__ float Hl[32 * DIM];
    __shared__ float bs[2][DIM];
    int t = threadIdx.x;
    float f0 = fw[0], f1 = fw[1];
    float m = fmaxf(f0, f1);
    float e0 = expf(f0 - m), e1 = expf(f1 - m);
    float sw0 = e0 / (e0 + e1), sw1 = e1 / (e0 + e1);
    if (t < 128) {
        float s = 0.f;
        for (int i = 0; i <= NORDER; ++i) s += bO[i * DIM + t];
        bs[0][t] = s;
    } else {
        int j = t - 128;
        float s = 0.f;
        for (int i = 0; i <= NORDER; ++i) s += bA[i * DIM + j];
        bs[1][j] = s;
    }
    for (int i = 0; i < 8; ++i) {
        int idx = (i * 256 + t) * 4;
        *(float4*)&Wl[idx] = *(const float4*)&clfW[idx];
    }
    __syncthreads();
    int rowBase = blockIdx.x * 32;
    for (int i = 0; i < 4; ++i) {
        int idx = (i * 256 + t) * 4;
        int kcol = idx & 127;
        float4 a = *(const float4*)&accO[rowBase * DIM + idx];
        float4 b = *(const float4*)&accA[rowBase * DIM + idx];
        float4 h;
        h.x = sw0 * fmaxf(a.x + bs[0][kcol + 0], 0.f) + sw1 * fmaxf(b.x + bs[1][kcol + 0], 0.f);
        h.y = sw0 * fmaxf(a.y + bs[0][kcol + 1], 0.f) + sw1 * fmaxf(b.y + bs[1][kcol + 1], 0.f);
        h.z = sw0 * fmaxf(a.z + bs[0][kcol + 2], 0.f) + sw1 * fmaxf(b.z + bs[1][kcol + 2], 0.f);
        h.w = sw0 * fmaxf(a.w + bs[0][kcol + 3], 0.f) + sw1 * fmaxf(b.w + bs[1][kcol + 3], 0.f);
        *(float4*)&Hl[idx] = h;
    }
    __syncthreads();
    int lane = t & 63, w = t >> 6;
    int c2 = (lane & 31) * 2;
    int r0 = w * 8 + (lane >> 5) * 4;
    float acc[4][2];
    for (int j = 0; j < 4; ++j) { acc[j][0] = 0.f; acc[j][1] = 0.f; }
    for (int k0 = 0; k0 < DIM; k0 += 4) {
        float4 a0 = *(const float4*)&Hl[(r0 + 0) * DIM + k0];
        float4 a1 = *(const float4*)&Hl[(r0 + 1) * DIM + k0];
        float4 a2 = *(const float4*)&Hl[(r0 + 2) * DIM + k0];
        float4 a3 = *(const float4*)&Hl[(r0 + 3) * DIM + k0];
#define FSTEP(comp, kk)                                                      \
        {                                                                    \
            float2 wv = *(const float2*)&Wl[(k0 + kk) * ODIM + c2];          \
            acc[0][0] += a0.comp * wv.x; acc[0][1] += a0.comp * wv.y;        \
            acc[1][0] += a1.comp * wv.x; acc[1][1] += a1.comp * wv.y;        \
            acc[2][0] += a2.comp * wv.x; acc[2][1] += a2.comp * wv.y;        \
            acc[3][0] += a3.comp * wv.x; acc[3][1] += a3.comp * wv.y;        \
        }
        FSTEP(x, 0) FSTEP(y, 1) FSTEP(z, 2) FSTEP(w, 3)
#undef FSTEP
    }
    float2 cb2 = *(const float2*)&clfB[c2];
    for (int j = 0; j < 4; ++j) {
        float2 o = make_float2(acc[j][0] + cb2.x, acc[j][1] + cb2.y);
        *(float2*)&out[(rowBase + r0 + j) * ODIM + c2] = o;
    }
}

// ---------------------------------------------------------------------------
extern "C" void kernel_launch(void* const* d_in, const int* in_sizes, int n_in,
                              void* d_out, int out_size, void* d_ws, size_t ws_size,
                              hipStream_t stream) {
    const float* x   = (const float*)d_in[0];
    const int*   ei  = (const int*)d_in[1];
    const int*   gi  = (const int*)d_in[2];
    const float* w_o = (const float*)d_in[3];
    const float* b_o = (const float*)d_in[4];
    const float* w_a = (const float*)d_in[5];
    const float* b_a = (const float*)d_in[6];
    const float* fw  = (const float*)d_in[7];
    const float* cw  = (const float*)d_in[8];
    const float* cb  = (const float*)d_in[9];
    float* out = (float*)d_out;

    char* p = (char*)d_ws;
    auto alloc = [&](size_t bytes) {
        void* r = (void*)p;
        p += (bytes + 255) & ~(size_t)255;
        return r;
    };
    unsigned* Tbig = (unsigned*)alloc((size_t)NPAD * 320 * 4);        // [NPAD][640] fp16
    float* acc_o = (float*)alloc((size_t)NPAD * DIM * 4);
    float* acc_a = (float*)alloc((size_t)NPAD * DIM * 4);
    unsigned short* Wt = (unsigned short*)alloc((size_t)2 * 5 * DIM * DIM * 2);
    float* dinv  = (float*)alloc((size_t)N_NODES * 4);
    int2* pairs  = (int2*)alloc((size_t)NE * 8);
    int* csr_src = (int*)alloc((size_t)NE * 4);
    int* csr_ptr = (int*)alloc((size_t)(N_NODES + 1) * 4);
    int* cnt     = (int*)alloc((size_t)N_NODES * 4);
    int* bsum    = (int*)alloc(128 * 4);
    int* bhist   = (int*)alloc((size_t)NB * 4);
    int* boff    = (int*)alloc((size_t)(NB + 1) * 4);
    int* bcursor = (int*)alloc((size_t)NB * 4);

    const int gN  = (N_NODES + 255) / 256;          // 391
    const int gH2 = (NE + 2047) / 2048;             // 782
    const int gH4 = (NE + 4095) / 4096;             // 391
    const int gS  = (N_NODES + 1023) / 1024;        // 98
    const int gP  = (N_NODES * 64 + 255) / 256;     // 25000
    const int gX  = (NPAD * 64 + 255) / 256;        // 25024
    const int gW  = (2 * 5 * DIM * DIM + 255) / 256;
    const int gM  = NPAD / 128;                     // 782
    const int gF  = N_NODES / 32;                   // 3125

    xcast<<<gX, 256, 0, stream>>>(x, Tbig);
    wcast<<<gW, 256, 0, stream>>>(w_o, w_a, Wt);

    for (int g = 0; g < 2; ++g) {
        const int* edges = g ? gi : ei;
        const int* rowp = edges;
        const int* colp = edges + NE;
        float* acc = g ? acc_a : acc_o;
        const unsigned short* Wtg = Wt + (size_t)g * 5 * DIM * DIM;

        zero_b<<<2, 256, 0, stream>>>(bhist);
        hist_edges<<<gH2, 256, 0, stream>>>(colp, bhist);
        bscan<<<1, 64, 0, stream>>>(bhist, boff, bcursor);
        part_edges<<<gH4, 256, 0, stream>>>(rowp, colp, bcursor, pairs);
        count_fine<<<NB, 256, 0, stream>>>(pairs, boff, cnt);
        scan_block<<<gS, 256, 0, stream>>>(cnt, csr_ptr, bsum);
        scan_mid<<<1, 64, 0, stream>>>(bsum, gS);
        scan_add<<<gN, 256, 0, stream>>>(csr_ptr, bsum, cnt, dinv);
        fine_csr<<<NB, 256, 0, stream>>>(pairs, boff, csr_ptr, csr_src);

        for (int i = 1; i <= NORDER; ++i)
            propagate<<<gP, 256, 0, stream>>>(Tbig + (i - 1) * 64, Tbig + i * 64,
                                              csr_ptr, csr_src, dinv);

        gemmK<<<gM, 256, 0, stream>>>((const unsigned short*)Tbig, Wtg, acc);
    }
    fuse_clf<<<gF, 256, 0, stream>>>(acc_o, acc_a, b_o, b_a, fw, cw, cb, out);
}

// Round 8
// 864.586 us; speedup vs baseline: 2.3014x; 1.0841x over previous
//
#include <hip/hip_runtime.h>

#define N_NODES 100000
#define NPAD    100096      // multiple of 128 for GEMM tiles
#define NE      1600000
#define DIM     128
#define ODIM    64
#define NORDER  4
#define KTOT    640         // 5 * 128, T stored as one M x 640 matrix
#define NB      391         // buckets of 256 nodes (node >> 8)

typedef _Float16 h8 __attribute__((ext_vector_type(8)));
typedef float f4 __attribute__((ext_vector_type(4)));

__device__ __forceinline__ float2 up2(unsigned p) {
    union { unsigned u; _Float16 h[2]; } c; c.u = p;
    return make_float2((float)c.h[0], (float)c.h[1]);
}
__device__ __forceinline__ unsigned pk2(float x, float y) {
    union { unsigned u; _Float16 h[2]; } c;
    c.h[0] = (_Float16)x; c.h[1] = (_Float16)y;
    return c.u;
}
__device__ __forceinline__ unsigned short f2hbits(float x) {
    union { _Float16 h; unsigned short s; } c;
    c.h = (_Float16)x;
    return c.s;
}
__device__ __forceinline__ void async_cp16(const void* g, void* l) {
    __builtin_amdgcn_global_load_lds((const __attribute__((address_space(1))) void*)g,
                                     (__attribute__((address_space(3))) void*)l, 16, 0, 0);
}

// ---------------------------------------------------------------------------
// CSR build — both graphs per kernel; no per-node global atomics;
// pairs packed to 4 B: (row << 8) | (col & 255)
// ---------------------------------------------------------------------------

// bucket histogram (LDS-resident, flush once per block). grid = 2*782.
__global__ __launch_bounds__(256) void hist_edges(const int* __restrict__ e0,
                                                  const int* __restrict__ e1,
                                                  int* __restrict__ bhist) {
    __shared__ int lh[NB];
    int t = threadIdx.x;
    int g = blockIdx.x >= 782;
    int blk = g ? (blockIdx.x - 782) : blockIdx.x;
    const int* colp = (g ? e1 : e0) + NE;
    int* bh = bhist + g * NB;
    for (int i = t; i < NB; i += 256) lh[i] = 0;
    __syncthreads();
    int base = blk * 2048 + t;
#pragma unroll
    for (int j = 0; j < 8; ++j) {
        int e = base + j * 256;
        if (e < NE) atomicAdd(&lh[colp[e] >> 8], 1);
    }
    __syncthreads();
    for (int i = t; i < NB; i += 256) if (lh[i]) atomicAdd(&bh[i], lh[i]);
}

// wave-parallel exclusive scan of n entries per graph (wave = graph).
// oexcl has stride n+1 (oexcl[n] = total); ocur (stride n) optional copy.
__global__ void wave_scan(const int* __restrict__ in,
                          int* __restrict__ oexcl,
                          int* __restrict__ ocur,
                          int n, int with_cur) {
    int wv = threadIdx.x >> 6, lane = threadIdx.x & 63;
    if (wv >= 2) return;
    const int* I = in + wv * n;
    int* O = oexcl + wv * (n + 1);
    int* C = ocur + wv * n;
    int carry = 0;
    for (int base = 0; base < n; base += 64) {
        int i = base + lane;
        int v = (i < n) ? I[i] : 0;
        int s = v;
#pragma unroll
        for (int off = 1; off < 64; off <<= 1) {
            int x = __shfl_up(s, off, 64);
            if (lane >= off) s += x;
        }
        int excl = carry + s - v;
        if (i < n) {
            O[i] = excl;
            if (with_cur) C[i] = excl;
        }
        carry += __shfl(s, 63, 64);
    }
    if (lane == 0) O[n] = carry;
}

// partition edges into buckets; per-block chunks -> write-local lines.
// grid = 2*391.
__global__ __launch_bounds__(256) void part_edges(const int* __restrict__ e0,
                                                  const int* __restrict__ e1,
                                                  int* __restrict__ bcursor,
                                                  unsigned* __restrict__ pairs) {
    __shared__ int lh[NB];
    __shared__ int lpos[NB];
    int t = threadIdx.x;
    int g = blockIdx.x >= NB;
    int blk = g ? (blockIdx.x - NB) : blockIdx.x;
    const int* rowp = (g ? e1 : e0);
    const int* colp = rowp + NE;
    int* bc = bcursor + g * NB;
    unsigned* pr = pairs + (size_t)g * NE;
    for (int i = t; i < NB; i += 256) lh[i] = 0;
    __syncthreads();
    int base = blk * 4096 + t;
    int rank[16];
    short bk[16];
    unsigned char lcv[16];
#pragma unroll
    for (int j = 0; j < 16; ++j) {
        int e = base + j * 256;
        rank[j] = -1;
        if (e < NE) {
            int c = colp[e];
            bk[j] = (short)(c >> 8);
            lcv[j] = (unsigned char)(c & 255);
            rank[j] = atomicAdd(&lh[c >> 8], 1);
        }
    }
    __syncthreads();
    for (int i = t; i < NB; i += 256) {
        int n = lh[i];
        lpos[i] = n ? atomicAdd(&bc[i], n) : 0;
    }
    __syncthreads();
#pragma unroll
    for (int j = 0; j < 16; ++j) {
        int e = base + j * 256;
        if (e < NE) {
            int b = bk[j];
            pr[lpos[b] + rank[j]] = ((unsigned)rowp[e] << 8) | lcv[j];
        }
    }
}

// per-bucket: degree count (LDS), block-exclusive scan -> ptrv (bucket-local),
// bucket total -> bsum, dinv. grid = 2*391.
__global__ __launch_bounds__(256) void cnt_scan(const unsigned* __restrict__ pairs,
                                                const int* __restrict__ boff,
                                                int* __restrict__ ptrv,
                                                float* __restrict__ dinv,
                                                int* __restrict__ bsum) {
    __shared__ int lcnt[256];
    __shared__ int lscan[256];
    int t = threadIdx.x;
    int g = blockIdx.x >= NB;
    int b = g ? (blockIdx.x - NB) : blockIdx.x;
    const unsigned* pr = pairs + (size_t)g * NE;
    const int* bo = boff + g * (NB + 1);
    int* pv = ptrv + g * (N_NODES + 1);
    float* dv = dinv + g * N_NODES;
    int* bs = bsum + g * NB;
    lcnt[t] = 0;
    __syncthreads();
    int s = bo[b], e = bo[b + 1];
    for (int i = s + t; i < e; i += 256)
        atomicAdd(&lcnt[pr[i] & 255u], 1);
    __syncthreads();
    int v = lcnt[t];
    lscan[t] = v;
    __syncthreads();
    for (int off = 1; off < 256; off <<= 1) {
        int x = (t >= off) ? lscan[t - off] : 0;
        __syncthreads();
        lscan[t] += x;
        __syncthreads();
    }
    int node = (b << 8) + t;
    if (node < N_NODES) {
        pv[node] = lscan[t] - v;          // bucket-local exclusive
        dv[node] = rsqrtf((float)(v + 1));
    }
    if (t == 255) bs[b] = lscan[255];
}

// ptrv[i] += bmid[bucket]; ptrv[N] = NE. grid = 2*391.
__global__ __launch_bounds__(256) void scan_addk(int* __restrict__ ptrv,
                                                 const int* __restrict__ bmid) {
    int t = threadIdx.x;
    int g = blockIdx.x >= NB;
    int b = g ? (blockIdx.x - NB) : blockIdx.x;
    int* pv = ptrv + g * (N_NODES + 1);
    const int* bm = bmid + g * (NB + 1);
    int node = (b << 8) + t;
    if (node < N_NODES) pv[node] += bm[b];
    if (b == 0 && t == 0) pv[N_NODES] = NE;
}

// fine scatter: one block per bucket; per-node counters in LDS; csr_src
// writes land in a contiguous window owned by this block. grid = 2*391.
__global__ __launch_bounds__(256) void fine_csr(const unsigned* __restrict__ pairs,
                                                const int* __restrict__ boff,
                                                const int* __restrict__ ptrv,
                                                int* __restrict__ srcv) {
    __shared__ int lcnt[256];
    int t = threadIdx.x;
    int g = blockIdx.x >= NB;
    int b = g ? (blockIdx.x - NB) : blockIdx.x;
    const unsigned* pr = pairs + (size_t)g * NE;
    const int* bo = boff + g * (NB + 1);
    const int* pv = ptrv + g * (N_NODES + 1);
    int* sv = srcv + (size_t)g * NE;
    lcnt[t] = 0;
    __syncthreads();
    int s = bo[b], e = bo[b + 1];
    int base = b << 8;
    for (int i = s + t; i < e; i += 256) {
        unsigned pk = pr[i];
        int lc = (int)(pk & 255u);
        int pos = pv[base + lc] + atomicAdd(&lcnt[lc], 1);
        sv[pos] = (int)(pk >> 8);
    }
}

// ---------------------------------------------------------------------------
// casts
// ---------------------------------------------------------------------------
// x -> slice 0 of Tbig [NPAD][640] fp16 (row stride 320 uints)
__global__ __launch_bounds__(256) void xcast(const float* __restrict__ x,
                                             unsigned* __restrict__ Tbig) {
    int idx = blockIdx.x * 256 + threadIdx.x;
    if (idx >= NPAD * 64) return;
    int m = idx >> 6, u = idx & 63;
    int e = (m << 7) + u * 2;
    float a = (m < N_NODES) ? x[e]     : 0.f;
    float b = (m < N_NODES) ? x[e + 1] : 0.f;
    Tbig[m * 320 + u] = pk2(a, b);
}

// Wt[g][i][k8][n][k7] = (half) W_g[i][k8*8+k7][n]   (chunk-transposed for LDS)
__global__ __launch_bounds__(256) void wcast(const float* __restrict__ Wo,
                                             const float* __restrict__ Wa,
                                             unsigned short* __restrict__ Wt) {
    int idx = blockIdx.x * 256 + threadIdx.x;
    if (idx >= 2 * 5 * DIM * DIM) return;
    int g   = idx / (5 * DIM * DIM);
    int rem = idx % (5 * DIM * DIM);
    int i   = rem / (DIM * DIM);
    int r2  = rem % (DIM * DIM);
    int k8  = r2 >> 10;
    int n   = (r2 >> 3) & 127;
    int k7  = r2 & 7;
    int k   = k8 * 8 + k7;
    const float* W = g ? Wa : Wo;
    Wt[idx] = f2hbits(W[(i * DIM + k) * DIM + n]);
}

// ---------------------------------------------------------------------------
// Propagation: one wave per node; scalar pipe for metadata, vector pipe
// carries only the 256 B row gathers, 16-deep. (At 6.45 TB/s effective —
// fabric roofline.)
// ---------------------------------------------------------------------------
__global__ __launch_bounds__(256) void propagate(const unsigned* __restrict__ Tin,
                                                 unsigned* __restrict__ Tout,
                                                 const int* __restrict__ ptrv,
                                                 const int* __restrict__ srcv,
                                                 const float* __restrict__ dinv) {
    int gid  = blockIdx.x * 256 + threadIdx.x;
    int lane = threadIdx.x & 63;
    int v    = __builtin_amdgcn_readfirstlane(gid >> 6);
    if (v >= N_NODES) return;
    float dv = dinv[v];
    float2 self = up2(Tin[v * 320 + lane]);
    float ax = dv * dv * self.x;
    float ay = dv * dv * self.y;
    int beg = ptrv[v], end = ptrv[v + 1];
    int k = beg;
    for (; k + 16 <= end; k += 16) {
        int u[16];
#pragma unroll
        for (int j = 0; j < 16; ++j) u[j] = srcv[k + j];
        float2 tt[16];
#pragma unroll
        for (int j = 0; j < 16; ++j) tt[j] = up2(Tin[u[j] * 320 + lane]);
        float w[16];
#pragma unroll
        for (int j = 0; j < 16; ++j) w[j] = dinv[u[j]] * dv;
#pragma unroll
        for (int j = 0; j < 16; ++j) { ax += w[j] * tt[j].x; ay += w[j] * tt[j].y; }
    }
    for (; k + 4 <= end; k += 4) {
        int u[4];
#pragma unroll
        for (int j = 0; j < 4; ++j) u[j] = srcv[k + j];
        float2 tt[4];
#pragma unroll
        for (int j = 0; j < 4; ++j) tt[j] = up2(Tin[u[j] * 320 + lane]);
        float w[4];
#pragma unroll
        for (int j = 0; j < 4; ++j) w[j] = dinv[u[j]] * dv;
#pragma unroll
        for (int j = 0; j < 4; ++j) { ax += w[j] * tt[j].x; ay += w[j] * tt[j].y; }
    }
    for (; k < end; ++k) {
        int u = srcv[k];
        float w = dinv[u] * dv;
        float2 t = up2(Tin[u * 320 + lane]);
        ax += w * t.x; ay += w * t.y;
    }
    Tout[v * 320 + lane] = pk2(ax, ay);
}

// ---------------------------------------------------------------------------
// C[M x 128] = A[M x 640] @ W[640 x 128] via fp16 MFMA.
// ---------------------------------------------------------------------------
__global__ __launch_bounds__(256, 3) void gemmK(const unsigned short* __restrict__ A,
                                                const unsigned short* __restrict__ Wt,
                                                float* __restrict__ C) {
    __shared__ unsigned short Bl[DIM * DIM];   // 32 KB
    int t = threadIdx.x;
    int lane = t & 63, wv = t >> 6;
    int m0 = blockIdx.x * 128 + wv * 32;
    int l15 = lane & 15, q = lane >> 4;
    f4 acc[2][8];
#pragma unroll
    for (int mt = 0; mt < 2; ++mt)
#pragma unroll
        for (int nt = 0; nt < 8; ++nt) acc[mt][nt] = (f4)(0.f);

#pragma unroll
    for (int i = 0; i < 5; ++i) {
        const unsigned short* WtI = Wt + (size_t)i * DIM * DIM;
        h8 af[2][4];
#pragma unroll
        for (int mt = 0; mt < 2; ++mt)
#pragma unroll
            for (int kc = 0; kc < 4; ++kc)
                af[mt][kc] = *(const h8*)(A + (size_t)(m0 + mt * 16 + l15) * KTOT
                                            + i * DIM + (kc * 4 + q) * 8);
#pragma unroll
        for (int c = 0; c < 8; ++c) {
            int ci = c * 4 + wv;
            async_cp16(WtI + ci * 512 + lane * 8, &Bl[ci * 512]);
        }
        __syncthreads();
#pragma unroll
        for (int kc = 0; kc < 4; ++kc) {
            int c = kc * 4 + q;
#pragma unroll
            for (int nt = 0; nt < 8; ++nt) {
                h8 bf = *(const h8*)&Bl[(size_t)(c * 128 + nt * 16 + l15) * 8];
                acc[0][nt] = __builtin_amdgcn_mfma_f32_16x16x32_f16(af[0][kc], bf, acc[0][nt], 0, 0, 0);
                acc[1][nt] = __builtin_amdgcn_mfma_f32_16x16x32_f16(af[1][kc], bf, acc[1][nt], 0, 0, 0);
            }
        }
        __syncthreads();
    }
#pragma unroll
    for (int mt = 0; mt < 2; ++mt)
#pragma unroll
        for (int nt = 0; nt < 8; ++nt)
#pragma unroll
            for (int r = 0; r < 4; ++r)
                C[(size_t)(m0 + mt * 16 + q * 4 + r) * DIM + nt * 16 + l15] = acc[mt][nt][r];
}

// ---------------------------------------------------------------------------
// out = (w0*relu(accO + sum bO) + w1*relu(accA + sum bA)) @ clfW + clfB
// ---------------------------------------------------------------------------
__global__ __launch_bounds__(256) void fuse_clf(const float* __restrict__ accO,
                                                const float* __restrict__ accA,
                                                const float* __restrict__ bO,
                                                const float* __restrict__ bA,
                                                const float* __restrict__ fw,
                                                const float* __restrict__ clfW,
                                                const float* __restrict__ clfB,
                                                float* __restrict__ out) {
    __shared__ float Wl[DIM * ODIM];
    __shared__ float Hl[32 * DIM];
    __shared__ float bs[2][DIM];
    int t = threadIdx.x;
    float f0 = fw[0], f1 = fw[1];
    float m = fmaxf(f0, f1);
    float e0 = expf(f0 - m), e1 = expf(f1 - m);
    float sw0 = e0 / (e0 + e1), sw1 = e1 / (e0 + e1);
    if (t < 128) {
        float s = 0.f;
        for (int i = 0; i <= NORDER; ++i) s += bO[i * DIM + t];
        bs[0][t] = s;
    } else {
        int j = t - 128;
        float s = 0.f;
        for (int i = 0; i <= NORDER; ++i) s += bA[i * DIM + j];
        bs[1][j] = s;
    }
    for (int i = 0; i < 8; ++i) {
        int idx = (i * 256 + t) * 4;
        *(float4*)&Wl[idx] = *(const float4*)&clfW[idx];
    }
    __syncthreads();
    int rowBase = blockIdx.x * 32;
    for (int i = 0; i < 4; ++i) {
        int idx = (i * 256 + t) * 4;
        int kcol = idx & 127;
        float4 a = *(const float4*)&accO[rowBase * DIM + idx];
        float4 b = *(const float4*)&accA[rowBase * DIM + idx];
        float4 h;
        h.x = sw0 * fmaxf(a.x + bs[0][kcol + 0], 0.f) + sw1 * fmaxf(b.x + bs[1][kcol + 0], 0.f);
        h.y = sw0 * fmaxf(a.y + bs[0][kcol + 1], 0.f) + sw1 * fmaxf(b.y + bs[1][kcol + 1], 0.f);
        h.z = sw0 * fmaxf(a.z + bs[0][kcol + 2], 0.f) + sw1 * fmaxf(b.z + bs[1][kcol + 2], 0.f);
        h.w = sw0 * fmaxf(a.w + bs[0][kcol + 3], 0.f) + sw1 * fmaxf(b.w + bs[1][kcol + 3], 0.f);
        *(float4*)&Hl[idx] = h;
    }
    __syncthreads();
    int lane = t & 63, w = t >> 6;
    int c2 = (lane & 31) * 2;
    int r0 = w * 8 + (lane >> 5) * 4;
    float acc[4][2];
    for (int j = 0; j < 4; ++j) { acc[j][0] = 0.f; acc[j][1] = 0.f; }
    for (int k0 = 0; k0 < DIM; k0 += 4) {
        float4 a0 = *(const float4*)&Hl[(r0 + 0) * DIM + k0];
        float4 a1 = *(const float4*)&Hl[(r0 + 1) * DIM + k0];
        float4 a2 = *(const float4*)&Hl[(r0 + 2) * DIM + k0];
        float4 a3 = *(const float4*)&Hl[(r0 + 3) * DIM + k0];
#define FSTEP(comp, kk)                                                      \
        {                                                                    \
            float2 wv = *(const float2*)&Wl[(k0 + kk) * ODIM + c2];          \
            acc[0][0] += a0.comp * wv.x; acc[0][1] += a0.comp * wv.y;        \
            acc[1][0] += a1.comp * wv.x; acc[1][1] += a1.comp * wv.y;        \
            acc[2][0] += a2.comp * wv.x; acc[2][1] += a2.comp * wv.y;        \
            acc[3][0] += a3.comp * wv.x; acc[3][1] += a3.comp * wv.y;        \
        }
        FSTEP(x, 0) FSTEP(y, 1) FSTEP(z, 2) FSTEP(w, 3)
#undef FSTEP
    }
    float2 cb2 = *(const float2*)&clfB[c2];
    for (int j = 0; j < 4; ++j) {
        float2 o = make_float2(acc[j][0] + cb2.x, acc[j][1] + cb2.y);
        *(float2*)&out[(rowBase + r0 + j) * ODIM + c2] = o;
    }
}

// ---------------------------------------------------------------------------
extern "C" void kernel_launch(void* const* d_in, const int* in_sizes, int n_in,
                              void* d_out, int out_size, void* d_ws, size_t ws_size,
                              hipStream_t stream) {
    const float* x   = (const float*)d_in[0];
    const int*   ei  = (const int*)d_in[1];
    const int*   gi  = (const int*)d_in[2];
    const float* w_o = (const float*)d_in[3];
    const float* b_o = (const float*)d_in[4];
    const float* w_a = (const float*)d_in[5];
    const float* b_a = (const float*)d_in[6];
    const float* fw  = (const float*)d_in[7];
    const float* cw  = (const float*)d_in[8];
    const float* cb  = (const float*)d_in[9];
    float* out = (float*)d_out;

    char* p = (char*)d_ws;
    auto alloc = [&](size_t bytes) {
        void* r = (void*)p;
        p += (bytes + 255) & ~(size_t)255;
        return r;
    };
    unsigned* Tbig = (unsigned*)alloc((size_t)NPAD * 320 * 4);        // [NPAD][640] fp16
    float* acc_o = (float*)alloc((size_t)NPAD * DIM * 4);
    float* acc_a = (float*)alloc((size_t)NPAD * DIM * 4);
    unsigned short* Wt = (unsigned short*)alloc((size_t)2 * 5 * DIM * DIM * 2);
    float* dinv  = (float*)alloc((size_t)2 * N_NODES * 4);
    unsigned* pairs = (unsigned*)alloc((size_t)2 * NE * 4);
    int* csr_src = (int*)alloc((size_t)2 * NE * 4);
    int* csr_ptr = (int*)alloc((size_t)2 * (N_NODES + 1) * 4);
    int* bhist   = (int*)alloc((size_t)2 * NB * 4);
    int* boff    = (int*)alloc((size_t)2 * (NB + 1) * 4);
    int* bcursor = (int*)alloc((size_t)2 * NB * 4);
    int* bsum    = (int*)alloc((size_t)2 * NB * 4);
    int* bmid    = (int*)alloc((size_t)2 * (NB + 1) * 4);

    const int gP  = (N_NODES * 64 + 255) / 256;     // 25000
    const int gX  = (NPAD * 64 + 255) / 256;        // 25024
    const int gW  = (2 * 5 * DIM * DIM + 255) / 256;
    const int gM  = NPAD / 128;                     // 782
    const int gF  = N_NODES / 32;                   // 3125

    xcast<<<gX, 256, 0, stream>>>(x, Tbig);
    wcast<<<gW, 256, 0, stream>>>(w_o, w_a, Wt);

    // ---- CSR build for BOTH graphs (merged kernels) ----
    hipMemsetAsync(bhist, 0, (size_t)2 * NB * 4, stream);
    hist_edges<<<2 * 782, 256, 0, stream>>>(ei, gi, bhist);
    wave_scan<<<1, 128, 0, stream>>>(bhist, boff, bcursor, NB, 1);
    part_edges<<<2 * NB, 256, 0, stream>>>(ei, gi, bcursor, pairs);
    cnt_scan<<<2 * NB, 256, 0, stream>>>(pairs, boff, csr_ptr, dinv, bsum);
    wave_scan<<<1, 128, 0, stream>>>(bsum, bmid, bcursor, NB, 0);
    scan_addk<<<2 * NB, 256, 0, stream>>>(csr_ptr, bmid);
    fine_csr<<<2 * NB, 256, 0, stream>>>(pairs, boff, csr_ptr, csr_src);

    // ---- per-branch propagate + GEMM (Tbig slices reused across branches) --
    for (int g = 0; g < 2; ++g) {
        float* acc = g ? acc_a : acc_o;
        const unsigned short* Wtg = Wt + (size_t)g * 5 * DIM * DIM;
        const int* pv = csr_ptr + g * (N_NODES + 1);
        const int* sv = csr_src + (size_t)g * NE;
        const float* dv = dinv + (size_t)g * N_NODES;

        for (int i = 1; i <= NORDER; ++i)
            propagate<<<gP, 256, 0, stream>>>(Tbig + (i - 1) * 64, Tbig + i * 64,
                                              pv, sv, dv);

        gemmK<<<gM, 256, 0, stream>>>((const unsigned short*)Tbig, Wtg, acc);
    }
    fuse_clf<<<gF, 256, 0, stream>>>(acc_o, acc_a, b_o, b_a, fw, cw, cb, out);
}

// Round 11
// 818.247 us; speedup vs baseline: 2.4317x; 1.0566x over previous
//
#include <hip/hip_runtime.h>

#define N_NODES 100000
#define NPAD    100096      // multiple of 128 for GEMM tiles
#define NE      1600000
#define DIM     128
#define ODIM    64
#define NORDER  4
#define KTOT    640         // 5 * 128, T stored as one M x 640 matrix
#define NB      391         // buckets of 256 nodes (node >> 8)
#define PB_EDGES 16384      // edges per part_edges block
#define PB_BLKS  98         // ceil(NE / PB_EDGES)

typedef _Float16 h8 __attribute__((ext_vector_type(8)));
typedef float f4 __attribute__((ext_vector_type(4)));

__device__ __forceinline__ float2 up2(unsigned p) {
    union { unsigned u; _Float16 h[2]; } c; c.u = p;
    return make_float2((float)c.h[0], (float)c.h[1]);
}
__device__ __forceinline__ unsigned pk2(float x, float y) {
    union { unsigned u; _Float16 h[2]; } c;
    c.h[0] = (_Float16)x; c.h[1] = (_Float16)y;
    return c.u;
}
__device__ __forceinline__ unsigned short f2hbits(float x) {
    union { _Float16 h; unsigned short s; } c;
    c.h = (_Float16)x;
    return c.s;
}
__device__ __forceinline__ float h2f(unsigned short s) {
    union { unsigned short u; _Float16 h; } c;
    c.u = s;
    return (float)c.h;
}
__device__ __forceinline__ void async_cp16(const void* g, void* l) {
    __builtin_amdgcn_global_load_lds((const __attribute__((address_space(1))) void*)g,
                                     (__attribute__((address_space(3))) void*)l, 16, 0, 0);
}

// ---------------------------------------------------------------------------
// CSR build — both graphs per kernel; no per-node global atomics;
// pairs packed to 4 B: (row << 8) | (col & 255)
// ---------------------------------------------------------------------------
__global__ __launch_bounds__(256) void hist_edges(const int* __restrict__ e0,
                                                  const int* __restrict__ e1,
                                                  int* __restrict__ bhist) {
    __shared__ int lh[NB];
    int t = threadIdx.x;
    int g = blockIdx.x >= 782;
    int blk = g ? (blockIdx.x - 782) : blockIdx.x;
    const int* colp = (g ? e1 : e0) + NE;
    int* bh = bhist + g * NB;
    for (int i = t; i < NB; i += 256) lh[i] = 0;
    __syncthreads();
    int base = blk * 2048 + t;
#pragma unroll
    for (int j = 0; j < 8; ++j) {
        int e = base + j * 256;
        if (e < NE) atomicAdd(&lh[colp[e] >> 8], 1);
    }
    __syncthreads();
    for (int i = t; i < NB; i += 256) if (lh[i]) atomicAdd(&bh[i], lh[i]);
}

__global__ void wave_scan(const int* __restrict__ in,
                          int* __restrict__ oexcl,
                          int* __restrict__ ocur,
                          int n, int with_cur) {
    int wv = threadIdx.x >> 6, lane = threadIdx.x & 63;
    if (wv >= 2) return;
    const int* I = in + wv * n;
    int* O = oexcl + wv * (n + 1);
    int* C = ocur + wv * n;
    int carry = 0;
    for (int base = 0; base < n; base += 64) {
        int i = base + lane;
        int v = (i < n) ? I[i] : 0;
        int s = v;
#pragma unroll
        for (int off = 1; off < 64; off <<= 1) {
            int x = __shfl_up(s, off, 64);
            if (lane >= off) s += x;
        }
        int excl = carry + s - v;
        if (i < n) {
            O[i] = excl;
            if (with_cur) C[i] = excl;
        }
        carry += __shfl(s, 63, 64);
    }
    if (lane == 0) O[n] = carry;
}

// 16384 edges/block -> per-bucket chunks avg ~168 B (single-writer lines)
__global__ __launch_bounds__(1024) void part_edges(const int* __restrict__ e0,
                                                   const int* __restrict__ e1,
                                                   int* __restrict__ bcursor,
                                                   unsigned* __restrict__ pairs) {
    __shared__ int lh[NB];
    __shared__ int lpos[NB];
    int t = threadIdx.x;
    int g = blockIdx.x >= PB_BLKS;
    int blk = g ? (blockIdx.x - PB_BLKS) : blockIdx.x;
    const int* rowp = (g ? e1 : e0);
    const int* colp = rowp + NE;
    int* bc = bcursor + g * NB;
    unsigned* pr = pairs + (size_t)g * NE;
    for (int i = t; i < NB; i += 1024) lh[i] = 0;
    __syncthreads();
    int base = blk * PB_EDGES + t;
    int rank[16];
    short bk[16];
    unsigned char lcv[16];
#pragma unroll
    for (int j = 0; j < 16; ++j) {
        int e = base + j * 1024;
        rank[j] = -1;
        if (e < NE) {
            int c = colp[e];
            bk[j] = (short)(c >> 8);
            lcv[j] = (unsigned char)(c & 255);
            rank[j] = atomicAdd(&lh[c >> 8], 1);
        }
    }
    __syncthreads();
    for (int i = t; i < NB; i += 1024) {
        int n = lh[i];
        lpos[i] = n ? atomicAdd(&bc[i], n) : 0;
    }
    __syncthreads();
#pragma unroll
    for (int j = 0; j < 16; ++j) {
        int e = base + j * 1024;
        if (e < NE) {
            int b = bk[j];
            pr[lpos[b] + rank[j]] = ((unsigned)rowp[e] << 8) | lcv[j];
        }
    }
}

__global__ __launch_bounds__(256) void cnt_scan(const unsigned* __restrict__ pairs,
                                                const int* __restrict__ boff,
                                                int* __restrict__ ptrv,
                                                float* __restrict__ dinv,
                                                int* __restrict__ bsum) {
    __shared__ int lcnt[256];
    __shared__ int lscan[256];
    int t = threadIdx.x;
    int g = blockIdx.x >= NB;
    int b = g ? (blockIdx.x - NB) : blockIdx.x;
    const unsigned* pr = pairs + (size_t)g * NE;
    const int* bo = boff + g * (NB + 1);
    int* pv = ptrv + g * (N_NODES + 1);
    float* dv = dinv + g * N_NODES;
    int* bs = bsum + g * NB;
    lcnt[t] = 0;
    __syncthreads();
    int s = bo[b], e = bo[b + 1];
    for (int i = s + t; i < e; i += 256)
        atomicAdd(&lcnt[pr[i] & 255u], 1);
    __syncthreads();
    int v = lcnt[t];
    lscan[t] = v;
    __syncthreads();
    for (int off = 1; off < 256; off <<= 1) {
        int x = (t >= off) ? lscan[t - off] : 0;
        __syncthreads();
        lscan[t] += x;
        __syncthreads();
    }
    int node = (b << 8) + t;
    if (node < N_NODES) {
        pv[node] = lscan[t] - v;
        dv[node] = rsqrtf((float)(v + 1));
    }
    if (t == 255) bs[b] = lscan[255];
}

__global__ __launch_bounds__(256) void scan_addk(int* __restrict__ ptrv,
                                                 const int* __restrict__ bmid) {
    int t = threadIdx.x;
    int g = blockIdx.x >= NB;
    int b = g ? (blockIdx.x - NB) : blockIdx.x;
    int* pv = ptrv + g * (N_NODES + 1);
    const int* bm = bmid + g * (NB + 1);
    int node = (b << 8) + t;
    if (node < N_NODES) pv[node] += bm[b];
    if (b == 0 && t == 0) pv[N_NODES] = NE;
}

__global__ __launch_bounds__(256) void fine_csr(const unsigned* __restrict__ pairs,
                                                const int* __restrict__ boff,
                                                const int* __restrict__ ptrv,
                                                int* __restrict__ srcv) {
    __shared__ int lcnt[256];
    int t = threadIdx.x;
    int g = blockIdx.x >= NB;
    int b = g ? (blockIdx.x - NB) : blockIdx.x;
    const unsigned* pr = pairs + (size_t)g * NE;
    const int* bo = boff + g * (NB + 1);
    const int* pv = ptrv + g * (N_NODES + 1);
    int* sv = srcv + (size_t)g * NE;
    lcnt[t] = 0;
    __syncthreads();
    int s = bo[b], e = bo[b + 1];
    int base = b << 8;
    for (int i = s + t; i < e; i += 256) {
        unsigned pk = pr[i];
        int lc = (int)(pk & 255u);
        int pos = pv[base + lc] + atomicAdd(&lcnt[lc], 1);
        sv[pos] = (int)(pk >> 8);
    }
}

// ---------------------------------------------------------------------------
// casts
// ---------------------------------------------------------------------------
__global__ __launch_bounds__(256) void xcast(const float* __restrict__ x,
                                             unsigned* __restrict__ Tbig) {
    int idx = blockIdx.x * 256 + threadIdx.x;
    if (idx >= NPAD * 64) return;
    int m = idx >> 6, u = idx & 63;
    int e = (m << 7) + u * 2;
    float a = (m < N_NODES) ? x[e]     : 0.f;
    float b = (m < N_NODES) ? x[e + 1] : 0.f;
    Tbig[m * 320 + u] = pk2(a, b);
}

// Wt[g][i][k8][n][k7] = (half) W_g[i][k8*8+k7][n]; tail: clfWt[n][k]=clfW[k][n]
__global__ __launch_bounds__(256) void wcast(const float* __restrict__ Wo,
                                             const float* __restrict__ Wa,
                                             const float* __restrict__ cw,
                                             unsigned short* __restrict__ Wt) {
    int idx = blockIdx.x * 256 + threadIdx.x;
    if (idx >= 2 * 5 * DIM * DIM + ODIM * DIM) return;
    if (idx < 2 * 5 * DIM * DIM) {
        int g   = idx / (5 * DIM * DIM);
        int rem = idx % (5 * DIM * DIM);
        int i   = rem / (DIM * DIM);
        int r2  = rem % (DIM * DIM);
        int k8  = r2 >> 10;
        int n   = (r2 >> 3) & 127;
        int k7  = r2 & 7;
        int k   = k8 * 8 + k7;
        const float* W = g ? Wa : Wo;
        Wt[idx] = f2hbits(W[(i * DIM + k) * DIM + n]);
    } else {
        int j = idx - 2 * 5 * DIM * DIM;
        int n = j >> 7, k = j & 127;
        Wt[idx] = f2hbits(cw[k * ODIM + n]);
    }
}

// ---------------------------------------------------------------------------
// Propagation (at fabric roofline: ~6.45 TB/s effective)
// ---------------------------------------------------------------------------
__global__ __launch_bounds__(256) void propagate(const unsigned* __restrict__ Tin,
                                                 unsigned* __restrict__ Tout,
                                                 const int* __restrict__ ptrv,
                                                 const int* __restrict__ srcv,
                                                 const float* __restrict__ dinv) {
    int gid  = blockIdx.x * 256 + threadIdx.x;
    int lane = threadIdx.x & 63;
    int v    = __builtin_amdgcn_readfirstlane(gid >> 6);
    if (v >= N_NODES) return;
    float dv = dinv[v];
    float2 self = up2(Tin[v * 320 + lane]);
    float ax = dv * dv * self.x;
    float ay = dv * dv * self.y;
    int beg = ptrv[v], end = ptrv[v + 1];
    int k = beg;
    for (; k + 16 <= end; k += 16) {
        int u[16];
#pragma unroll
        for (int j = 0; j < 16; ++j) u[j] = srcv[k + j];
        float2 tt[16];
#pragma unroll
        for (int j = 0; j < 16; ++j) tt[j] = up2(Tin[u[j] * 320 + lane]);
        float w[16];
#pragma unroll
        for (int j = 0; j < 16; ++j) w[j] = dinv[u[j]] * dv;
#pragma unroll
        for (int j = 0; j < 16; ++j) { ax += w[j] * tt[j].x; ay += w[j] * tt[j].y; }
    }
    for (; k + 4 <= end; k += 4) {
        int u[4];
#pragma unroll
        for (int j = 0; j < 4; ++j) u[j] = srcv[k + j];
        float2 tt[4];
#pragma unroll
        for (int j = 0; j < 4; ++j) tt[j] = up2(Tin[u[j] * 320 + lane]);
        float w[4];
#pragma unroll
        for (int j = 0; j < 4; ++j) w[j] = dinv[u[j]] * dv;
#pragma unroll
        for (int j = 0; j < 4; ++j) { ax += w[j] * tt[j].x; ay += w[j] * tt[j].y; }
    }
    for (; k < end; ++k) {
        int u = srcv[k];
        float w = dinv[u] * dv;
        float2 t = up2(Tin[u * 320 + lane]);
        ax += w * t.x; ay += w * t.y;
    }
    Tout[v * 320 + lane] = pk2(ax, ay);
}

// ---------------------------------------------------------------------------
// Branch-0 GEMM: H0[m][n] = fp16( sw0 * relu( (A @ W0)[m][n] + bs0[n] ) )
// A = Tbig [NPAD][640] fp16. Block 256 thr / 4 waves, 128 rows.
// ---------------------------------------------------------------------------
__global__ __launch_bounds__(256, 2) void gemmH0(
        const unsigned short* __restrict__ A,
        const unsigned short* __restrict__ Wt,
        const float* __restrict__ bO,
        const float* __restrict__ fw,
        unsigned short* __restrict__ H0) {
    __shared__ unsigned short Bl[DIM * DIM];   // 32 KB
    __shared__ float bsl[DIM];
    int t = threadIdx.x;
    int lane = t & 63, wv = t >> 6;
    int m0 = blockIdx.x * 128 + wv * 32;
    int l15 = lane & 15, q = lane >> 4;
    if (t < 128) {
        float s = 0.f;
        for (int i = 0; i <= NORDER; ++i) s += bO[i * DIM + t];
        bsl[t] = s;
    }
    float f0 = fw[0], f1 = fw[1];
    float mx = fmaxf(f0, f1);
    float e0 = expf(f0 - mx), e1 = expf(f1 - mx);
    float sw0 = e0 / (e0 + e1);

    f4 acc[2][8];
#pragma unroll
    for (int mt = 0; mt < 2; ++mt)
#pragma unroll
        for (int nt = 0; nt < 8; ++nt) acc[mt][nt] = (f4)(0.f);

#pragma unroll
    for (int i = 0; i < 5; ++i) {
        const unsigned short* WtI = Wt + (size_t)i * DIM * DIM;
        h8 af[2][4];
#pragma unroll
        for (int mt = 0; mt < 2; ++mt)
#pragma unroll
            for (int kc = 0; kc < 4; ++kc)
                af[mt][kc] = *(const h8*)(A + (size_t)(m0 + mt * 16 + l15) * KTOT
                                            + i * DIM + (kc * 4 + q) * 8);
#pragma unroll
        for (int c = 0; c < 8; ++c) {
            int ci = c * 4 + wv;
            async_cp16(WtI + ci * 512 + lane * 8, &Bl[ci * 512]);
        }
        __syncthreads();
#pragma unroll
        for (int kc = 0; kc < 4; ++kc) {
            int c = kc * 4 + q;
#pragma unroll
            for (int nt = 0; nt < 8; ++nt) {
                h8 bf = *(const h8*)&Bl[(size_t)(c * 128 + nt * 16 + l15) * 8];
                acc[0][nt] = __builtin_amdgcn_mfma_f32_16x16x32_f16(af[0][kc], bf, acc[0][nt], 0, 0, 0);
                acc[1][nt] = __builtin_amdgcn_mfma_f32_16x16x32_f16(af[1][kc], bf, acc[1][nt], 0, 0, 0);
            }
        }
        __syncthreads();
    }
#pragma unroll
    for (int mt = 0; mt < 2; ++mt)
#pragma unroll
        for (int nt = 0; nt < 8; ++nt) {
            float bsv = bsl[nt * 16 + l15];
#pragma unroll
            for (int r = 0; r < 4; ++r) {
                int row = m0 + mt * 16 + q * 4 + r;
                H0[(size_t)row * DIM + nt * 16 + l15] =
                    f2hbits(sw0 * fmaxf(acc[mt][nt][r] + bsv, 0.f));
            }
        }
}

// ---------------------------------------------------------------------------
// Branch-1 GEMM + fusion + classifier:
// acc1 = A @ W1 (regs); H = sw1*relu(acc1+bs1) + H0 (global fp16);
// H -> LDS (C-layout -> A-frag layout, stride 132); out = H @ clfW + clfB.
// LDS: BlH aliased (staging Bl first DIM*DIM, later Hl 128x132) = 33792 B.
// ---------------------------------------------------------------------------
__global__ __launch_bounds__(256, 2) void gemm_fused2(
        const unsigned short* __restrict__ A,
        const unsigned short* __restrict__ Wt,
        const unsigned short* __restrict__ H0,
        const float* __restrict__ bA,
        const float* __restrict__ fw,
        const unsigned short* __restrict__ clfWt,
        const float* __restrict__ clfB,
        float* __restrict__ out) {
    __shared__ unsigned short BlH[DIM * 132];
    __shared__ float bsl[DIM];
    unsigned short* Bl = BlH;
    unsigned short* Hl = BlH;
    int t = threadIdx.x;
    int lane = t & 63, wv = t >> 6;
    int m0 = blockIdx.x * 128 + wv * 32;
    int l15 = lane & 15, q = lane >> 4;
    if (t < 128) {
        float s = 0.f;
        for (int i = 0; i <= NORDER; ++i) s += bA[i * DIM + t];
        bsl[t] = s;
    }
    float f0 = fw[0], f1 = fw[1];
    float mx = fmaxf(f0, f1);
    float e0 = expf(f0 - mx), e1 = expf(f1 - mx);
    float sw1 = e1 / (e0 + e1);

    f4 acc[2][8];
#pragma unroll
    for (int mt = 0; mt < 2; ++mt)
#pragma unroll
        for (int nt = 0; nt < 8; ++nt) acc[mt][nt] = (f4)(0.f);

#pragma unroll
    for (int i = 0; i < 5; ++i) {
        const unsigned short* WtI = Wt + (size_t)i * DIM * DIM;
        h8 af[2][4];
#pragma unroll
        for (int mt = 0; mt < 2; ++mt)
#pragma unroll
            for (int kc = 0; kc < 4; ++kc)
                af[mt][kc] = *(const h8*)(A + (size_t)(m0 + mt * 16 + l15) * KTOT
                                            + i * DIM + (kc * 4 + q) * 8);
#pragma unroll
        for (int c = 0; c < 8; ++c) {
            int ci = c * 4 + wv;
            async_cp16(WtI + ci * 512 + lane * 8, &Bl[ci * 512]);
        }
        __syncthreads();
#pragma unroll
        for (int kc = 0; kc < 4; ++kc) {
            int c = kc * 4 + q;
#pragma unroll
            for (int nt = 0; nt < 8; ++nt) {
                h8 bf = *(const h8*)&Bl[(size_t)(c * 128 + nt * 16 + l15) * 8];
                acc[0][nt] = __builtin_amdgcn_mfma_f32_16x16x32_f16(af[0][kc], bf, acc[0][nt], 0, 0, 0);
                acc[1][nt] = __builtin_amdgcn_mfma_f32_16x16x32_f16(af[1][kc], bf, acc[1][nt], 0, 0, 0);
            }
        }
        __syncthreads();
    }

    // fuse with H0 and write H into LDS (aliases the now-dead staging buffer)
#pragma unroll
    for (int mt = 0; mt < 2; ++mt)
#pragma unroll
        for (int nt = 0; nt < 8; ++nt) {
            float bsv = bsl[nt * 16 + l15];
            int col = nt * 16 + l15;
#pragma unroll
            for (int r = 0; r < 4; ++r) {
                int lrow = wv * 32 + mt * 16 + q * 4 + r;
                int grow = m0 + mt * 16 + q * 4 + r;
                float h = sw1 * fmaxf(acc[mt][nt][r] + bsv, 0.f)
                        + h2f(H0[(size_t)grow * DIM + col]);
                Hl[lrow * 132 + col] = f2hbits(h);
            }
        }
    __syncthreads();

    f4 o[2][4];
#pragma unroll
    for (int mt = 0; mt < 2; ++mt)
#pragma unroll
        for (int n2 = 0; n2 < 4; ++n2) o[mt][n2] = (f4)(0.f);
#pragma unroll
    for (int kc = 0; kc < 4; ++kc) {
        int c = kc * 4 + q;
        h8 ha[2];
#pragma unroll
        for (int mt = 0; mt < 2; ++mt)
            ha[mt] = *(const h8*)&Hl[(wv * 32 + mt * 16 + l15) * 132 + c * 8];
#pragma unroll
        for (int n2 = 0; n2 < 4; ++n2) {
            h8 bf = *(const h8*)&clfWt[(size_t)(n2 * 16 + l15) * DIM + c * 8];
            o[0][n2] = __builtin_amdgcn_mfma_f32_16x16x32_f16(ha[0], bf, o[0][n2], 0, 0, 0);
            o[1][n2] = __builtin_amdgcn_mfma_f32_16x16x32_f16(ha[1], bf, o[1][n2], 0, 0, 0);
        }
    }
#pragma unroll
    for (int mt = 0; mt < 2; ++mt)
#pragma unroll
        for (int n2 = 0; n2 < 4; ++n2) {
            int col = n2 * 16 + l15;
            float cbv = clfB[col];
#pragma unroll
            for (int r = 0; r < 4; ++r) {
                int row = m0 + mt * 16 + q * 4 + r;
                if (row < N_NODES) out[(size_t)row * ODIM + col] = o[mt][n2][r] + cbv;
            }
        }
}

// ---------------------------------------------------------------------------
extern "C" void kernel_launch(void* const* d_in, const int* in_sizes, int n_in,
                              void* d_out, int out_size, void* d_ws, size_t ws_size,
                              hipStream_t stream) {
    const float* x   = (const float*)d_in[0];
    const int*   ei  = (const int*)d_in[1];
    const int*   gi  = (const int*)d_in[2];
    const float* w_o = (const float*)d_in[3];
    const float* b_o = (const float*)d_in[4];
    const float* w_a = (const float*)d_in[5];
    const float* b_a = (const float*)d_in[6];
    const float* fw  = (const float*)d_in[7];
    const float* cw  = (const float*)d_in[8];
    const float* cb  = (const float*)d_in[9];
    float* out = (float*)d_out;

    char* p = (char*)d_ws;
    auto alloc = [&](size_t bytes) {
        void* r = (void*)p;
        p += (bytes + 255) & ~(size_t)255;
        return r;
    };
    // total ~181.3 MB (< 256 MiB; round-8's proven budget was 258 MB)
    unsigned* Tbig = (unsigned*)alloc((size_t)NPAD * 320 * 4);          // 128.1 MB
    unsigned short* H0 = (unsigned short*)alloc((size_t)NPAD * DIM * 2); // 25.6 MB
    unsigned short* Wt = (unsigned short*)alloc(((size_t)2 * 5 * DIM * DIM + ODIM * DIM) * 2);
    float* dinv  = (float*)alloc((size_t)2 * N_NODES * 4);
    unsigned* pairs = (unsigned*)alloc((size_t)2 * NE * 4);             // 12.8 MB
    int* csr_src = (int*)alloc((size_t)2 * NE * 4);                     // 12.8 MB
    int* csr_ptr = (int*)alloc((size_t)2 * (N_NODES + 1) * 4);
    int* bhist   = (int*)alloc((size_t)2 * NB * 4);
    int* boff    = (int*)alloc((size_t)2 * (NB + 1) * 4);
    int* bcursor = (int*)alloc((size_t)2 * NB * 4);
    int* bsum    = (int*)alloc((size_t)2 * NB * 4);
    int* bmid    = (int*)alloc((size_t)2 * (NB + 1) * 4);

    const int gP  = (N_NODES * 64 + 255) / 256;     // 25000
    const int gX  = (NPAD * 64 + 255) / 256;        // 25024
    const int gW  = (2 * 5 * DIM * DIM + ODIM * DIM + 255) / 256;
    const int gM  = NPAD / 128;                     // 782

    xcast<<<gX, 256, 0, stream>>>(x, Tbig);
    wcast<<<gW, 256, 0, stream>>>(w_o, w_a, cw, Wt);

    // ---- CSR build for BOTH graphs (merged kernels) ----
    hipMemsetAsync(bhist, 0, (size_t)2 * NB * 4, stream);
    hist_edges<<<2 * 782, 256, 0, stream>>>(ei, gi, bhist);
    wave_scan<<<1, 128, 0, stream>>>(bhist, boff, bcursor, NB, 1);
    part_edges<<<2 * PB_BLKS, 1024, 0, stream>>>(ei, gi, bcursor, pairs);
    cnt_scan<<<2 * NB, 256, 0, stream>>>(pairs, boff, csr_ptr, dinv, bsum);
    wave_scan<<<1, 128, 0, stream>>>(bsum, bmid, bcursor, NB, 0);
    scan_addk<<<2 * NB, 256, 0, stream>>>(csr_ptr, bmid);
    fine_csr<<<2 * NB, 256, 0, stream>>>(pairs, boff, csr_ptr, csr_src);

    // ---- branch 0: propagate (slices 1-4), GEMM -> H0 fp16 ----
    for (int i = 1; i <= NORDER; ++i)
        propagate<<<gP, 256, 0, stream>>>(Tbig + (i - 1) * 64, Tbig + i * 64,
                                          csr_ptr, csr_src, dinv);
    gemmH0<<<gM, 256, 0, stream>>>((const unsigned short*)Tbig, Wt, b_o, fw, H0);

    // ---- branch 1: slice 0 (x) untouched; overwrite slices 1-4 ----
    {
        const int* pv = csr_ptr + (N_NODES + 1);
        const int* sv = csr_src + (size_t)NE;
        const float* dv = dinv + (size_t)N_NODES;
        for (int i = 1; i <= NORDER; ++i)
            propagate<<<gP, 256, 0, stream>>>(Tbig + (i - 1) * 64, Tbig + i * 64,
                                              pv, sv, dv);
    }
    gemm_fused2<<<gM, 256, 0, stream>>>((const unsigned short*)Tbig,
                                        Wt + (size_t)5 * DIM * DIM,
                                        H0, b_a, fw,
                                        Wt + (size_t)2 * 5 * DIM * DIM, cb, out);
}

// Round 12
// 809.167 us; speedup vs baseline: 2.4590x; 1.0112x over previous
//
#include <hip/hip_runtime.h>

#define N_NODES 100000
#define NPAD    100096      // multiple of 128 for GEMM tiles
#define NE      1600000
#define DIM     128
#define ODIM    64
#define NORDER  4
#define KTOT    640         // 5 * 128, T stored as one M x 640 matrix
#define NB      391         // buckets of 256 nodes (node >> 8)
#define PB_EDGES 16384      // edges per part_edges block
#define PB_BLKS  98         // ceil(NE / PB_EDGES)

typedef _Float16 h8 __attribute__((ext_vector_type(8)));
typedef float f4 __attribute__((ext_vector_type(4)));

__device__ __forceinline__ float2 up2(unsigned p) {
    union { unsigned u; _Float16 h[2]; } c; c.u = p;
    return make_float2((float)c.h[0], (float)c.h[1]);
}
__device__ __forceinline__ unsigned pk2(float x, float y) {
    union { unsigned u; _Float16 h[2]; } c;
    c.h[0] = (_Float16)x; c.h[1] = (_Float16)y;
    return c.u;
}
__device__ __forceinline__ unsigned short f2hbits(float x) {
    union { _Float16 h; unsigned short s; } c;
    c.h = (_Float16)x;
    return c.s;
}
__device__ __forceinline__ float h2f(unsigned short s) {
    union { unsigned short u; _Float16 h; } c;
    c.u = s;
    return (float)c.h;
}
__device__ __forceinline__ void async_cp16(const void* g, void* l) {
    __builtin_amdgcn_global_load_lds((const __attribute__((address_space(1))) void*)g,
                                     (__attribute__((address_space(3))) void*)l, 16, 0, 0);
}

// ---------------------------------------------------------------------------
// CSR build — both graphs per kernel; no per-node global atomics;
// pairs packed to 4 B: (row << 8) | (col & 255).
// Chain: memset, hist, wave_scan, part, bucket_csr (5 dispatches).
// ---------------------------------------------------------------------------
__global__ __launch_bounds__(256) void hist_edges(const int* __restrict__ e0,
                                                  const int* __restrict__ e1,
                                                  int* __restrict__ bhist) {
    __shared__ int lh[NB];
    int t = threadIdx.x;
    int g = blockIdx.x >= 782;
    int blk = g ? (blockIdx.x - 782) : blockIdx.x;
    const int* colp = (g ? e1 : e0) + NE;
    int* bh = bhist + g * NB;
    for (int i = t; i < NB; i += 256) lh[i] = 0;
    __syncthreads();
    int base = blk * 2048 + t;
#pragma unroll
    for (int j = 0; j < 8; ++j) {
        int e = base + j * 256;
        if (e < NE) atomicAdd(&lh[colp[e] >> 8], 1);
    }
    __syncthreads();
    for (int i = t; i < NB; i += 256) if (lh[i]) atomicAdd(&bh[i], lh[i]);
}

// wave-parallel exclusive scan (wave = graph): boff (stride NB+1) + bcursor copy
__global__ void wave_scan(const int* __restrict__ in,
                          int* __restrict__ oexcl,
                          int* __restrict__ ocur,
                          int n) {
    int wv = threadIdx.x >> 6, lane = threadIdx.x & 63;
    if (wv >= 2) return;
    const int* I = in + wv * n;
    int* O = oexcl + wv * (n + 1);
    int* C = ocur + wv * n;
    int carry = 0;
    for (int base = 0; base < n; base += 64) {
        int i = base + lane;
        int v = (i < n) ? I[i] : 0;
        int s = v;
#pragma unroll
        for (int off = 1; off < 64; off <<= 1) {
            int x = __shfl_up(s, off, 64);
            if (lane >= off) s += x;
        }
        int excl = carry + s - v;
        if (i < n) {
            O[i] = excl;
            C[i] = excl;
        }
        carry += __shfl(s, 63, 64);
    }
    if (lane == 0) O[n] = carry;
}

// 16384 edges/block -> per-bucket chunks avg ~168 B (single-writer lines)
__global__ __launch_bounds__(1024) void part_edges(const int* __restrict__ e0,
                                                   const int* __restrict__ e1,
                                                   int* __restrict__ bcursor,
                                                   unsigned* __restrict__ pairs) {
    __shared__ int lh[NB];
    __shared__ int lpos[NB];
    int t = threadIdx.x;
    int g = blockIdx.x >= PB_BLKS;
    int blk = g ? (blockIdx.x - PB_BLKS) : blockIdx.x;
    const int* rowp = (g ? e1 : e0);
    const int* colp = rowp + NE;
    int* bc = bcursor + g * NB;
    unsigned* pr = pairs + (size_t)g * NE;
    for (int i = t; i < NB; i += 1024) lh[i] = 0;
    __syncthreads();
    int base = blk * PB_EDGES + t;
    int rank[16];
    short bk[16];
    unsigned char lcv[16];
#pragma unroll
    for (int j = 0; j < 16; ++j) {
        int e = base + j * 1024;
        rank[j] = -1;
        if (e < NE) {
            int c = colp[e];
            bk[j] = (short)(c >> 8);
            lcv[j] = (unsigned char)(c & 255);
            rank[j] = atomicAdd(&lh[c >> 8], 1);
        }
    }
    __syncthreads();
    for (int i = t; i < NB; i += 1024) {
        int n = lh[i];
        lpos[i] = n ? atomicAdd(&bc[i], n) : 0;
    }
    __syncthreads();
#pragma unroll
    for (int j = 0; j < 16; ++j) {
        int e = base + j * 1024;
        if (e < NE) {
            int b = bk[j];
            pr[lpos[b] + rank[j]] = ((unsigned)rowp[e] << 8) | lcv[j];
        }
    }
}

// per-bucket, one kernel: degree count (LDS) -> block scan -> FINAL ptrv
// (= boff[b] + local excl; bsum[b]==bhist[b] so its prefix IS boff) + dinv,
// then reset counters and scatter src into the bucket's contiguous window.
__global__ __launch_bounds__(256) void bucket_csr(const unsigned* __restrict__ pairs,
                                                  const int* __restrict__ boff,
                                                  int* __restrict__ ptrv,
                                                  float* __restrict__ dinv,
                                                  int* __restrict__ srcv) {
    __shared__ int lcnt[256];
    __shared__ int lbase[256];   // final global ptrv per local node
    int t = threadIdx.x;
    int g = blockIdx.x >= NB;
    int b = g ? (blockIdx.x - NB) : blockIdx.x;
    const unsigned* pr = pairs + (size_t)g * NE;
    const int* bo = boff + g * (NB + 1);
    int* pv = ptrv + g * (N_NODES + 1);
    float* dv = dinv + g * N_NODES;
    int* sv = srcv + (size_t)g * NE;
    lcnt[t] = 0;
    __syncthreads();
    int s = bo[b], e = bo[b + 1];
    for (int i = s + t; i < e; i += 256)
        atomicAdd(&lcnt[pr[i] & 255u], 1);
    __syncthreads();
    int v = lcnt[t];
    // block exclusive scan over 256 degrees
    lbase[t] = v;
    __syncthreads();
    for (int off = 1; off < 256; off <<= 1) {
        int x = (t >= off) ? lbase[t - off] : 0;
        __syncthreads();
        lbase[t] += x;
        __syncthreads();
    }
    int node = (b << 8) + t;
    int gbase = s + lbase[t] - v;          // final global CSR offset
    lbase[t] = gbase;
    lcnt[t] = 0;                           // reset for scatter ranks
    if (node < N_NODES) {
        pv[node] = gbase;
        dv[node] = rsqrtf((float)(v + 1));
    }
    if (b == 0 && g == 0 && t == 0) ptrv[N_NODES] = NE;
    if (b == 0 && g == 1 && t == 0) ptrv[2 * N_NODES + 1] = NE;
    __syncthreads();
    for (int i = s + t; i < e; i += 256) {
        unsigned pk = pr[i];
        int lc = (int)(pk & 255u);
        int pos = lbase[lc] + atomicAdd(&lcnt[lc], 1);
        sv[pos] = (int)(pk >> 8);
    }
}

// ---------------------------------------------------------------------------
// casts
// ---------------------------------------------------------------------------
__global__ __launch_bounds__(256) void xcast(const float* __restrict__ x,
                                             unsigned* __restrict__ Tbig) {
    int idx = blockIdx.x * 256 + threadIdx.x;
    if (idx >= NPAD * 64) return;
    int m = idx >> 6, u = idx & 63;
    int e = (m << 7) + u * 2;
    float a = (m < N_NODES) ? x[e]     : 0.f;
    float b = (m < N_NODES) ? x[e + 1] : 0.f;
    Tbig[m * 320 + u] = pk2(a, b);
}

// Wt[g][i][k8][n][k7] = (half) W_g[i][k8*8+k7][n]; tail: clfWt[n][k]=clfW[k][n]
__global__ __launch_bounds__(256) void wcast(const float* __restrict__ Wo,
                                             const float* __restrict__ Wa,
                                             const float* __restrict__ cw,
                                             unsigned short* __restrict__ Wt) {
    int idx = blockIdx.x * 256 + threadIdx.x;
    if (idx >= 2 * 5 * DIM * DIM + ODIM * DIM) return;
    if (idx < 2 * 5 * DIM * DIM) {
        int g   = idx / (5 * DIM * DIM);
        int rem = idx % (5 * DIM * DIM);
        int i   = rem / (DIM * DIM);
        int r2  = rem % (DIM * DIM);
        int k8  = r2 >> 10;
        int n   = (r2 >> 3) & 127;
        int k7  = r2 & 7;
        int k   = k8 * 8 + k7;
        const float* W = g ? Wa : Wo;
        Wt[idx] = f2hbits(W[(i * DIM + k) * DIM + n]);
    } else {
        int j = idx - 2 * 5 * DIM * DIM;
        int n = j >> 7, k = j & 127;
        Wt[idx] = f2hbits(cw[k * ODIM + n]);
    }
}

// ---------------------------------------------------------------------------
// Propagation (at fabric roofline: ~6.45 TB/s effective)
// ---------------------------------------------------------------------------
__global__ __launch_bounds__(256) void propagate(const unsigned* __restrict__ Tin,
                                                 unsigned* __restrict__ Tout,
                                                 const int* __restrict__ ptrv,
                                                 const int* __restrict__ srcv,
                                                 const float* __restrict__ dinv) {
    int gid  = blockIdx.x * 256 + threadIdx.x;
    int lane = threadIdx.x & 63;
    int v    = __builtin_amdgcn_readfirstlane(gid >> 6);
    if (v >= N_NODES) return;
    float dv = dinv[v];
    float2 self = up2(Tin[v * 320 + lane]);
    float ax = dv * dv * self.x;
    float ay = dv * dv * self.y;
    int beg = ptrv[v], end = ptrv[v + 1];
    int k = beg;
    for (; k + 16 <= end; k += 16) {
        int u[16];
#pragma unroll
        for (int j = 0; j < 16; ++j) u[j] = srcv[k + j];
        float2 tt[16];
#pragma unroll
        for (int j = 0; j < 16; ++j) tt[j] = up2(Tin[u[j] * 320 + lane]);
        float w[16];
#pragma unroll
        for (int j = 0; j < 16; ++j) w[j] = dinv[u[j]] * dv;
#pragma unroll
        for (int j = 0; j < 16; ++j) { ax += w[j] * tt[j].x; ay += w[j] * tt[j].y; }
    }
    for (; k + 4 <= end; k += 4) {
        int u[4];
#pragma unroll
        for (int j = 0; j < 4; ++j) u[j] = srcv[k + j];
        float2 tt[4];
#pragma unroll
        for (int j = 0; j < 4; ++j) tt[j] = up2(Tin[u[j] * 320 + lane]);
        float w[4];
#pragma unroll
        for (int j = 0; j < 4; ++j) w[j] = dinv[u[j]] * dv;
#pragma unroll
        for (int j = 0; j < 4; ++j) { ax += w[j] * tt[j].x; ay += w[j] * tt[j].y; }
    }
    for (; k < end; ++k) {
        int u = srcv[k];
        float w = dinv[u] * dv;
        float2 t = up2(Tin[u * 320 + lane]);
        ax += w * t.x; ay += w * t.y;
    }
    Tout[v * 320 + lane] = pk2(ax, ay);
}

// ---------------------------------------------------------------------------
// Branch-0 GEMM: H0[m][n] = fp16( sw0 * relu( (A @ W0)[m][n] + bs0[n] ) )
// ---------------------------------------------------------------------------
__global__ __launch_bounds__(256, 3) void gemmH0(
        const unsigned short* __restrict__ A,
        const unsigned short* __restrict__ Wt,
        const float* __restrict__ bO,
        const float* __restrict__ fw,
        unsigned short* __restrict__ H0) {
    __shared__ unsigned short Bl[DIM * DIM];   // 32 KB
    __shared__ float bsl[DIM];
    int t = threadIdx.x;
    int lane = t & 63, wv = t >> 6;
    int m0 = blockIdx.x * 128 + wv * 32;
    int l15 = lane & 15, q = lane >> 4;
    if (t < 128) {
        float s = 0.f;
        for (int i = 0; i <= NORDER; ++i) s += bO[i * DIM + t];
        bsl[t] = s;
    }
    float f0 = fw[0], f1 = fw[1];
    float mx = fmaxf(f0, f1);
    float e0 = expf(f0 - mx), e1 = expf(f1 - mx);
    float sw0 = e0 / (e0 + e1);

    f4 acc[2][8];
#pragma unroll
    for (int mt = 0; mt < 2; ++mt)
#pragma unroll
        for (int nt = 0; nt < 8; ++nt) acc[mt][nt] = (f4)(0.f);

#pragma unroll
    for (int i = 0; i < 5; ++i) {
        const unsigned short* WtI = Wt + (size_t)i * DIM * DIM;
        h8 af[2][4];
#pragma unroll
        for (int mt = 0; mt < 2; ++mt)
#pragma unroll
            for (int kc = 0; kc < 4; ++kc)
                af[mt][kc] = *(const h8*)(A + (size_t)(m0 + mt * 16 + l15) * KTOT
                                            + i * DIM + (kc * 4 + q) * 8);
#pragma unroll
        for (int c = 0; c < 8; ++c) {
            int ci = c * 4 + wv;
            async_cp16(WtI + ci * 512 + lane * 8, &Bl[ci * 512]);
        }
        __syncthreads();
#pragma unroll
        for (int kc = 0; kc < 4; ++kc) {
            int c = kc * 4 + q;
#pragma unroll
            for (int nt = 0; nt < 8; ++nt) {
                h8 bf = *(const h8*)&Bl[(size_t)(c * 128 + nt * 16 + l15) * 8];
                acc[0][nt] = __builtin_amdgcn_mfma_f32_16x16x32_f16(af[0][kc], bf, acc[0][nt], 0, 0, 0);
                acc[1][nt] = __builtin_amdgcn_mfma_f32_16x16x32_f16(af[1][kc], bf, acc[1][nt], 0, 0, 0);
            }
        }
        __syncthreads();
    }
#pragma unroll
    for (int mt = 0; mt < 2; ++mt)
#pragma unroll
        for (int nt = 0; nt < 8; ++nt) {
            float bsv = bsl[nt * 16 + l15];
#pragma unroll
            for (int r = 0; r < 4; ++r) {
                int row = m0 + mt * 16 + q * 4 + r;
                H0[(size_t)row * DIM + nt * 16 + l15] =
                    f2hbits(sw0 * fmaxf(acc[mt][nt][r] + bsv, 0.f));
            }
        }
}

// ---------------------------------------------------------------------------
// Branch-1 GEMM + fusion + classifier (LDS aliased: Bl staging / Hl 128x132)
// ---------------------------------------------------------------------------
__global__ __launch_bounds__(256, 2) void gemm_fused2(
        const unsigned short* __restrict__ A,
        const unsigned short* __restrict__ Wt,
        const unsigned short* __restrict__ H0,
        const float* __restrict__ bA,
        const float* __restrict__ fw,
        const unsigned short* __restrict__ clfWt,
        const float* __restrict__ clfB,
        float* __restrict__ out) {
    __shared__ unsigned short BlH[DIM * 132];
    __shared__ float bsl[DIM];
    unsigned short* Bl = BlH;
    unsigned short* Hl = BlH;
    int t = threadIdx.x;
    int lane = t & 63, wv = t >> 6;
    int m0 = blockIdx.x * 128 + wv * 32;
    int l15 = lane & 15, q = lane >> 4;
    if (t < 128) {
        float s = 0.f;
        for (int i = 0; i <= NORDER; ++i) s += bA[i * DIM + t];
        bsl[t] = s;
    }
    float f0 = fw[0], f1 = fw[1];
    float mx = fmaxf(f0, f1);
    float e0 = expf(f0 - mx), e1 = expf(f1 - mx);
    float sw1 = e1 / (e0 + e1);

    f4 acc[2][8];
#pragma unroll
    for (int mt = 0; mt < 2; ++mt)
#pragma unroll
        for (int nt = 0; nt < 8; ++nt) acc[mt][nt] = (f4)(0.f);

#pragma unroll
    for (int i = 0; i < 5; ++i) {
        const unsigned short* WtI = Wt + (size_t)i * DIM * DIM;
        h8 af[2][4];
#pragma unroll
        for (int mt = 0; mt < 2; ++mt)
#pragma unroll
            for (int kc = 0; kc < 4; ++kc)
                af[mt][kc] = *(const h8*)(A + (size_t)(m0 + mt * 16 + l15) * KTOT
                                            + i * DIM + (kc * 4 + q) * 8);
#pragma unroll
        for (int c = 0; c < 8; ++c) {
            int ci = c * 4 + wv;
            async_cp16(WtI + ci * 512 + lane * 8, &Bl[ci * 512]);
        }
        __syncthreads();
#pragma unroll
        for (int kc = 0; kc < 4; ++kc) {
            int c = kc * 4 + q;
#pragma unroll
            for (int nt = 0; nt < 8; ++nt) {
                h8 bf = *(const h8*)&Bl[(size_t)(c * 128 + nt * 16 + l15) * 8];
                acc[0][nt] = __builtin_amdgcn_mfma_f32_16x16x32_f16(af[0][kc], bf, acc[0][nt], 0, 0, 0);
                acc[1][nt] = __builtin_amdgcn_mfma_f32_16x16x32_f16(af[1][kc], bf, acc[1][nt], 0, 0, 0);
            }
        }
        __syncthreads();
    }

    // fuse with H0 and write H into LDS (aliases the now-dead staging buffer)
#pragma unroll
    for (int mt = 0; mt < 2; ++mt)
#pragma unroll
        for (int nt = 0; nt < 8; ++nt) {
            float bsv = bsl[nt * 16 + l15];
            int col = nt * 16 + l15;
#pragma unroll
            for (int r = 0; r < 4; ++r) {
                int lrow = wv * 32 + mt * 16 + q * 4 + r;
                int grow = m0 + mt * 16 + q * 4 + r;
                float h = sw1 * fmaxf(acc[mt][nt][r] + bsv, 0.f)
                        + h2f(H0[(size_t)grow * DIM + col]);
                Hl[lrow * 132 + col] = f2hbits(h);
            }
        }
    __syncthreads();

    f4 o[2][4];
#pragma unroll
    for (int mt = 0; mt < 2; ++mt)
#pragma unroll
        for (int n2 = 0; n2 < 4; ++n2) o[mt][n2] = (f4)(0.f);
#pragma unroll
    for (int kc = 0; kc < 4; ++kc) {
        int c = kc * 4 + q;
        h8 ha[2];
#pragma unroll
        for (int mt = 0; mt < 2; ++mt)
            ha[mt] = *(const h8*)&Hl[(wv * 32 + mt * 16 + l15) * 132 + c * 8];
#pragma unroll
        for (int n2 = 0; n2 < 4; ++n2) {
            h8 bf = *(const h8*)&clfWt[(size_t)(n2 * 16 + l15) * DIM + c * 8];
            o[0][n2] = __builtin_amdgcn_mfma_f32_16x16x32_f16(ha[0], bf, o[0][n2], 0, 0, 0);
            o[1][n2] = __builtin_amdgcn_mfma_f32_16x16x32_f16(ha[1], bf, o[1][n2], 0, 0, 0);
        }
    }
#pragma unroll
    for (int mt = 0; mt < 2; ++mt)
#pragma unroll
        for (int n2 = 0; n2 < 4; ++n2) {
            int col = n2 * 16 + l15;
            float cbv = clfB[col];
#pragma unroll
            for (int r = 0; r < 4; ++r) {
                int row = m0 + mt * 16 + q * 4 + r;
                if (row < N_NODES) out[(size_t)row * ODIM + col] = o[mt][n2][r] + cbv;
            }
        }
}

// ---------------------------------------------------------------------------
extern "C" void kernel_launch(void* const* d_in, const int* in_sizes, int n_in,
                              void* d_out, int out_size, void* d_ws, size_t ws_size,
                              hipStream_t stream) {
    const float* x   = (const float*)d_in[0];
    const int*   ei  = (const int*)d_in[1];
    const int*   gi  = (const int*)d_in[2];
    const float* w_o = (const float*)d_in[3];
    const float* b_o = (const float*)d_in[4];
    const float* w_a = (const float*)d_in[5];
    const float* b_a = (const float*)d_in[6];
    const float* fw  = (const float*)d_in[7];
    const float* cw  = (const float*)d_in[8];
    const float* cb  = (const float*)d_in[9];
    float* out = (float*)d_out;

    char* p = (char*)d_ws;
    auto alloc = [&](size_t bytes) {
        void* r = (void*)p;
        p += (bytes + 255) & ~(size_t)255;
        return r;
    };
    // total ~181 MB (round-11 proven budget)
    unsigned* Tbig = (unsigned*)alloc((size_t)NPAD * 320 * 4);           // 128.1 MB
    unsigned short* H0 = (unsigned short*)alloc((size_t)NPAD * DIM * 2); // 25.6 MB
    unsigned short* Wt = (unsigned short*)alloc(((size_t)2 * 5 * DIM * DIM + ODIM * DIM) * 2);
    float* dinv  = (float*)alloc((size_t)2 * N_NODES * 4);
    unsigned* pairs = (unsigned*)alloc((size_t)2 * NE * 4);              // 12.8 MB
    int* csr_src = (int*)alloc((size_t)2 * NE * 4);                      // 12.8 MB
    int* csr_ptr = (int*)alloc((size_t)2 * (N_NODES + 1) * 4);
    int* bhist   = (int*)alloc((size_t)2 * NB * 4);
    int* boff    = (int*)alloc((size_t)2 * (NB + 1) * 4);
    int* bcursor = (int*)alloc((size_t)2 * NB * 4);

    const int gP  = (N_NODES * 64 + 255) / 256;     // 25000
    const int gX  = (NPAD * 64 + 255) / 256;        // 25024
    const int gW  = (2 * 5 * DIM * DIM + ODIM * DIM + 255) / 256;
    const int gM  = NPAD / 128;                     // 782

    xcast<<<gX, 256, 0, stream>>>(x, Tbig);
    wcast<<<gW, 256, 0, stream>>>(w_o, w_a, cw, Wt);

    // ---- CSR build for BOTH graphs: 5 dispatches ----
    hipMemsetAsync(bhist, 0, (size_t)2 * NB * 4, stream);
    hist_edges<<<2 * 782, 256, 0, stream>>>(ei, gi, bhist);
    wave_scan<<<1, 128, 0, stream>>>(bhist, boff, bcursor, NB);
    part_edges<<<2 * PB_BLKS, 1024, 0, stream>>>(ei, gi, bcursor, pairs);
    bucket_csr<<<2 * NB, 256, 0, stream>>>(pairs, boff, csr_ptr, dinv, csr_src);

    // ---- branch 0: propagate (slices 1-4), GEMM -> H0 fp16 ----
    for (int i = 1; i <= NORDER; ++i)
        propagate<<<gP, 256, 0, stream>>>(Tbig + (i - 1) * 64, Tbig + i * 64,
                                          csr_ptr, csr_src, dinv);
    gemmH0<<<gM, 256, 0, stream>>>((const unsigned short*)Tbig, Wt, b_o, fw, H0);

    // ---- branch 1: slice 0 (x) untouched; overwrite slices 1-4 ----
    {
        const int* pv = csr_ptr + (N_NODES + 1);
        const int* sv = csr_src + (size_t)NE;
        const float* dv = dinv + (size_t)N_NODES;
        for (int i = 1; i <= NORDER; ++i)
            propagate<<<gP, 256, 0, stream>>>(Tbig + (i - 1) * 64, Tbig + i * 64,
                                              pv, sv, dv);
    }
    gemm_fused2<<<gM, 256, 0, stream>>>((const unsigned short*)Tbig,
                                        Wt + (size_t)5 * DIM * DIM,
                                        H0, b_a, fw,
                                        Wt + (size_t)2 * 5 * DIM * DIM, cb, out);
}